// Round 4
// baseline (617.427 us; speedup 1.0000x reference)
//
#include <hip/hip_runtime.h>
#include <hip/hip_fp16.h>

#define NNODES 100000
#define NEDGES 1600000
#define NSUB   1000
#define MSUB   64
#define MHID   128
#define CAP    64     // max in-degree bucket capacity (Poisson(16): P(>=64) ~ 1e-20)
#define NCHUNK 768
#define CHUNK  2084   // ceil(NEDGES / NCHUNK)
#define WSHIFT 12     // dst windows of 4096 nodes -> 2 MB write window per phase
#define NWIN   25     // ceil(NNODES / 4096)

// ---------------- graph preprocessing ----------------

// Window-partitioned bucket fill. Block b: part = b&7 (XCD-aligned under the
// usual round-robin dispatch — locality heuristic only), chunk = b>>3.
// For each sub-phase the block scans its 8 KB dst chunk (L1-resident after
// pass 0) and scatters only edges whose dst window belongs to this
// (part, phase): write window = 4096 nodes * 512 B = 2 MB, L2-resident, so
// bucket lines fill before writeback.
__global__ __launch_bounds__(256) void k_fill(const int* __restrict__ src,
                                              const int* __restrict__ dst,
                                              const float* __restrict__ ew,
                                              int* __restrict__ cnt,
                                              int2* __restrict__ pairs) {
    int part  = blockIdx.x & 7;
    int chunk = blockIdx.x >> 3;
    int e0 = chunk * CHUNK;
    int e1 = e0 + CHUNK; if (e1 > NEDGES) e1 = NEDGES;
    for (int s = 0; s < 4; s++) {
        int w = part + 8 * s;
        if (w >= NWIN) break;
        for (int e = e0 + (int)threadIdx.x; e < e1; e += 256) {
            int d = dst[e];
            if ((d >> WSHIFT) == w) {
                int   sv = __builtin_nontemporal_load(src + e);
                float wv = __builtin_nontemporal_load(ew + e);
                int pos = atomicAdd(&cnt[d], 1);
                if (pos < CAP)
                    pairs[(size_t)d * CAP + pos] = make_int2(sv, __float_as_int(wv));
            }
        }
    }
}

// wave per node: deg = sum of bucket weights (coalesced, no atomics),
// dinv = rsqrt(deg+1), self_norm = dinv^2.
__global__ __launch_bounds__(256) void k_degsum(const int* __restrict__ cnt,
                                                const int2* __restrict__ pairs,
                                                float* __restrict__ dinv,
                                                float* __restrict__ self_norm) {
    int t = threadIdx.x, lane = t & 63;
    int n = blockIdx.x * 4 + (t >> 6);
    if (n >= NNODES) return;
    int cn = cnt[n]; if (cn > CAP) cn = CAP;
    int2 pr = pairs[(size_t)n * CAP + lane];
    float s = (lane < cn) ? __int_as_float(pr.y) : 0.0f;
    for (int off = 32; off > 0; off >>= 1) s += __shfl_down(s, off, 64);
    if (lane == 0) {
        float dv = rsqrtf(s + 1.0f);
        dinv[n] = dv;
        self_norm[n] = dv * dv;
    }
}

// wave per node: normalize bucket weights (w *= dinv[s]*dinv[d]) and pad the
// bucket to a multiple of 16 with (n, 0.0f) dummies. Coalesced 8 B/lane.
__global__ __launch_bounds__(256) void k_norm(const float* __restrict__ dinv,
                                              const int* __restrict__ cnt,
                                              int2* __restrict__ pairs) {
    int t = threadIdx.x, lane = t & 63;
    int n = blockIdx.x * 4 + (t >> 6);
    if (n >= NNODES) return;
    int cn = cnt[n]; if (cn > CAP) cn = CAP;
    int c16 = (cn + 15) & ~15;
    float dd = dinv[n];
    if (lane < c16) {
        int2 outp;
        if (lane < cn) {
            int2 pr = pairs[(size_t)n * CAP + lane];
            float w = __int_as_float(pr.y) * dd * dinv[pr.x];
            outp = make_int2(pr.x, __float_as_int(w));
        } else {
            outp = make_int2(n, 0);   // weight bits 0 == 0.0f
        }
        pairs[(size_t)n * CAP + lane] = outp;
    }
}

// ---------------- GEMM: [200000 x 64] @ [64 x 64] -> fp16 ----------------
// TR=false: X is fp32 (harness input). TR=true: X is fp16 agg, with fused
// per-column GraphNorm affine + ReLU.

template <bool TR>
__global__ __launch_bounds__(256) void k_gemm(const void* __restrict__ Xv,
                                              const float* __restrict__ Wg,
                                              __half* __restrict__ Y,
                                              const float* __restrict__ Acoef,
                                              const float* __restrict__ Bcoef) {
    __shared__ __align__(16) float Wl[64 * 64];
    int t = threadIdx.x;
    #pragma unroll
    for (int i = 0; i < 16; i++) Wl[i * 256 + t] = Wg[i * 256 + t];
    __syncthreads();

    int wid  = blockIdx.x * 4 + (t >> 6);
    int lane = t & 63;
    int c = wid & 1;
    int g = wid >> 1;
    int n = g * 64 + lane;
    if (n >= NNODES) return;
    int row = n * 2 + c;

    float4 xr[16];
    if constexpr (!TR) {
        const float* xp = (const float*)Xv + (size_t)row * 64;
        #pragma unroll
        for (int q = 0; q < 16; q++) xr[q] = ((const float4*)xp)[q];
    } else {
        const __half* xp = (const __half*)Xv + (size_t)row * 64;
        #pragma unroll
        for (int q = 0; q < 8; q++) {
            uint4 u = ((const uint4*)xp)[q];
            float2 a = __half22float2(*(const __half2*)&u.x);
            float2 b = __half22float2(*(const __half2*)&u.y);
            float2 cc = __half22float2(*(const __half2*)&u.z);
            float2 d = __half22float2(*(const __half2*)&u.w);
            xr[2 * q]     = make_float4(a.x, a.y, b.x, b.y);
            xr[2 * q + 1] = make_float4(cc.x, cc.y, d.x, d.y);
        }
        const float* A = Acoef + c * 64;
        const float* B = Bcoef + c * 64;
        #pragma unroll
        for (int q = 0; q < 16; q++) {
            float4 a = ((const float4*)A)[q];
            float4 b = ((const float4*)B)[q];
            xr[q].x = fmaxf(a.x * xr[q].x + b.x, 0.0f);
            xr[q].y = fmaxf(a.y * xr[q].y + b.y, 0.0f);
            xr[q].z = fmaxf(a.z * xr[q].z + b.z, 0.0f);
            xr[q].w = fmaxf(a.w * xr[q].w + b.w, 0.0f);
        }
    }

    __half* yp = Y + (size_t)row * 64;
    for (int jg = 0; jg < 16; jg++) {
        float4 acc = make_float4(0.f, 0.f, 0.f, 0.f);
        const float* xs = (const float*)xr;
        #pragma unroll
        for (int k = 0; k < 64; k++) {
            float xv = xs[k];
            float4 w4 = ((const float4*)(Wl + k * 64))[jg];
            acc.x += xv * w4.x; acc.y += xv * w4.y;
            acc.z += xv * w4.z; acc.w += xv * w4.w;
        }
        union { __half2 h2[2]; uint2 u2; } cv;
        cv.h2[0] = __floats2half2_rn(acc.x, acc.y);
        cv.h2[1] = __floats2half2_rn(acc.z, acc.w);
        ((uint2*)yp)[jg] = cv.u2;
    }
}

// ---------------- pull-style GCN aggregation (fp16 in, fp16 out) -----------
// One wave per node, both channels. Lane l covers flat half-offsets [2l,2l+1]
// -> one 4 B gather per neighbor covers both channels. Buckets padded to
// multiples of 16 -> branch-free loop, 16 gathers in flight. pairs loads are
// non-temporal (streamed once) to keep L2 for the 25.6 MB hw gather table.

__global__ __launch_bounds__(256) void k_prop(const __half* __restrict__ hw,
                                              const float* __restrict__ bias,
                                              const float* __restrict__ self_norm,
                                              const int* __restrict__ cnt,
                                              const int2* __restrict__ pairs,
                                              __half* __restrict__ agg) {
    int t = threadIdx.x;
    int lane = t & 63;
    int n = __builtin_amdgcn_readfirstlane(blockIdx.x * 4 + (t >> 6));
    if (n >= NNODES) return;

    int f = lane * 2;            // flat half-offset in [0,128), even
    int feat = f & 63;

    float2 bv = *(const float2*)(bias + feat);
    float sn = self_norm[n];
    float2 self = __half22float2(*(const __half2*)(hw + (size_t)n * 128 + f));
    float acc0 = bv.x + sn * self.x;
    float acc1 = bv.y + sn * self.y;

    int cn = cnt[n]; if (cn > CAP) cn = CAP;
    int c16 = (cn + 15) & ~15;
    const unsigned long long* pp = (const unsigned long long*)(pairs + (size_t)n * CAP);

    for (int p = 0; p < c16; p += 16) {
        const unsigned long long* q = pp + p;
        unsigned long long e[16];
        #pragma unroll
        for (int i = 0; i < 16; i++) e[i] = __builtin_nontemporal_load(q + i);
        float2 h[16];
        #pragma unroll
        for (int i = 0; i < 16; i++) {
            int s = (int)(e[i] & 0xffffffffu);
            h[i] = __half22float2(*(const __half2*)(hw + (size_t)s * 128 + f));
        }
        #pragma unroll
        for (int i = 0; i < 16; i++) {
            float w = __int_as_float((int)(e[i] >> 32));
            acc0 += w * h[i].x;
            acc1 += w * h[i].y;
        }
    }

    *(__half2*)(agg + (size_t)n * 128 + f) = __floats2half2_rn(acc0, acc1);
}

// ---------------- GraphNorm stats (sum, sumsq per column) ----------------

__global__ __launch_bounds__(256) void k_stats(const __half* __restrict__ agg,
                                               float* __restrict__ stats) {
    int t = threadIdx.x;
    int col = (t & 63) * 2;
    int rg  = t >> 6;
    float s0 = 0.f, s1 = 0.f, q0 = 0.f, q1 = 0.f;
    for (int r = blockIdx.x * 4 + rg; r < NNODES; r += gridDim.x * 4) {
        float2 v = __half22float2(*(const __half2*)(agg + (size_t)r * 128 + col));
        s0 += v.x; s1 += v.y; q0 += v.x * v.x; q1 += v.y * v.y;
    }
    atomicAdd(&stats[col], s0);     atomicAdd(&stats[col + 1], s1);
    atomicAdd(&stats[128 + col], q0); atomicAdd(&stats[128 + col + 1], q1);
}

__global__ void k_coef(float* stats, const float* __restrict__ gn_w,
                       const float* __restrict__ gn_b, const float* __restrict__ gn_ms) {
    int col = threadIdx.x;  // 128
    float inv_n = 1.0f / (float)NNODES;
    float mean = stats[col] * inv_n;
    float eh2  = stats[128 + col] * inv_n;
    int f = col & 63;
    float ms = gn_ms[f];
    float var = eh2 - 2.0f * ms * mean * mean + ms * ms * mean * mean;
    float A = gn_w[f] * rsqrtf(var + 1e-5f);
    stats[256 + col] = A;
    stats[384 + col] = gn_b[f] - A * ms * mean;
}

// ---------------- fused subgraph pooling + MLP head ----------------

__global__ __launch_bounds__(128) void k_head(const __half* __restrict__ agg,
                                              const int* __restrict__ subg,
                                              const float* __restrict__ mW1,
                                              const float* __restrict__ mb1,
                                              const float* __restrict__ mW2,
                                              const float* __restrict__ mb2,
                                              float* __restrict__ out) {
    __shared__ float pl[128];
    __shared__ float red[128];
    int s = blockIdx.x, t = threadIdx.x;
    int j = t & 63, half = t >> 6;
    const int* idx = subg + s * 64;
    float acc = 0.f;
    for (int m = half * 32; m < half * 32 + 32; m++) {
        int n = idx[m];
        acc += 0.5f * (__half2float(agg[(size_t)n * 128 + j]) +
                       __half2float(agg[(size_t)n * 128 + 64 + j]));
    }
    pl[half * 64 + j] = acc;
    __syncthreads();
    if (t < 64) pl[t] += pl[64 + t];
    __syncthreads();
    float h = mb1[t];
    #pragma unroll
    for (int k = 0; k < 64; k++) h += pl[k] * mW1[k * 128 + t];
    h = fmaxf(h, 0.0f);
    red[t] = h * mW2[t];
    __syncthreads();
    for (int off = 64; off > 0; off >>= 1) {
        if (t < off) red[t] += red[t + off];
        __syncthreads();
    }
    if (t == 0) out[s] = red[0] + mb2[0];
}

// ---------------- launcher ----------------

extern "C" void kernel_launch(void* const* d_in, const int* in_sizes, int n_in,
                              void* d_out, int out_size, void* d_ws, size_t ws_size,
                              hipStream_t stream) {
    const float* x     = (const float*)d_in[0];
    const int*   ei    = (const int*)d_in[1];
    const float* ew    = (const float*)d_in[2];
    const int*   subg  = (const int*)d_in[3];
    const float* W1    = (const float*)d_in[4];
    const float* b1    = (const float*)d_in[5];
    const float* gn_w  = (const float*)d_in[6];
    const float* gn_b  = (const float*)d_in[7];
    const float* gn_ms = (const float*)d_in[8];
    const float* W2    = (const float*)d_in[9];
    const float* b2    = (const float*)d_in[10];
    const float* mW1   = (const float*)d_in[11];
    const float* mb1   = (const float*)d_in[12];
    const float* mW2   = (const float*)d_in[13];
    const float* mb2   = (const float*)d_in[14];
    float* out = (float*)d_out;

    char* w = (char*)d_ws;
    size_t off = 0;
    auto alloc = [&](size_t bytes) {
        void* p = w + off;
        off = (off + bytes + 255) & ~(size_t)255;
        return p;
    };
    float*  dinv      = (float*) alloc((size_t)NNODES * 4);
    float*  self_norm = (float*) alloc((size_t)NNODES * 4);
    int*    cnt       = (int*)   alloc((size_t)NNODES * 4);
    int2*   pairs     = (int2*)  alloc((size_t)NNODES * CAP * 8);  // 51.2 MB
    __half* hw        = (__half*)alloc((size_t)NNODES * 128 * 2);  // 25.6 MB
    __half* agg       = (__half*)alloc((size_t)NNODES * 128 * 2);  // 25.6 MB
    float*  stats     = (float*) alloc(512 * 4);

    const int* src = ei;
    const int* dst = ei + NEDGES;

    hipMemsetAsync(cnt, 0, (size_t)NNODES * 4, stream);
    hipMemsetAsync(stats, 0, 512 * 4, stream);

    // preprocessing: partitioned fill, bucket-sum degrees, normalize+pad
    k_fill  <<<NCHUNK * 8, 256, 0, stream>>>(src, dst, ew, cnt, pairs);
    k_degsum<<<25000, 256, 0, stream>>>(cnt, pairs, dinv, self_norm);
    k_norm  <<<25000, 256, 0, stream>>>(dinv, cnt, pairs);

    // layer 1
    k_gemm<false><<<782, 256, 0, stream>>>(x, W1, hw, nullptr, nullptr);
    k_prop<<<25000, 256, 0, stream>>>(hw, b1, self_norm, cnt, pairs, agg);

    // GraphNorm coefficients
    k_stats<<<256, 256, 0, stream>>>(agg, stats);
    k_coef<<<1, 128, 0, stream>>>(stats, gn_w, gn_b, gn_ms);

    // layer 2 (GraphNorm+ReLU fused into GEMM2 input)
    k_gemm<true><<<782, 256, 0, stream>>>(agg, W2, hw, stats + 256, stats + 384);
    k_prop<<<25000, 256, 0, stream>>>(hw, b2, self_norm, cnt, pairs, agg);

    // fused pooling + MLP head
    k_head<<<NSUB, 128, 0, stream>>>(agg, subg, mW1, mb1, mW2, mb2, out);
}

// Round 5
// 524.850 us; speedup vs baseline: 1.1764x; 1.1764x over previous
//
#include <hip/hip_runtime.h>
#include <hip/hip_fp16.h>

#define NNODES 100000
#define NEDGES 1600000
#define NSUB   1000
#define MSUB   64
#define MHID   128
#define CAP    64     // max in-degree bucket capacity (Poisson(16): P(>=64) ~ 1e-20)

#define WSHIFT 9                         // 512-node dst windows
#define NWIN   ((NNODES + 511) >> 9)     // 196
#define NBLK   256                       // blocks for hist/scatter
#define CHUNK  (NEDGES / NBLK)           // 6250 exact

// ---------------- edge binning: counting sort by dst window ----------------

// per-block histogram of dst windows over this block's edge chunk
__global__ __launch_bounds__(256) void k_hist(const int* __restrict__ dst,
                                              int* __restrict__ block_counts) {
    __shared__ int hist[NWIN];
    int t = threadIdx.x, b = blockIdx.x;
    for (int i = t; i < NWIN; i += 256) hist[i] = 0;
    __syncthreads();
    int e0 = b * CHUNK;
    for (int e = e0 + t; e < e0 + CHUNK; e += 256)
        atomicAdd(&hist[dst[e] >> WSHIFT], 1);
    __syncthreads();
    for (int i = t; i < NWIN; i += 256) block_counts[b * NWIN + i] = hist[i];
}

// window totals + exclusive scan -> win_base[NWIN+1]
__global__ __launch_bounds__(256) void k_scan1(const int* __restrict__ block_counts,
                                               int* __restrict__ win_base) {
    __shared__ int arr[256];
    int t = threadIdx.x;
    int own = 0;
    if (t < NWIN) for (int b = 0; b < NBLK; b++) own += block_counts[b * NWIN + t];
    arr[t] = own;
    __syncthreads();
    for (int off = 1; off < 256; off <<= 1) {
        int v = (t >= off) ? arr[t - off] : 0;
        __syncthreads();
        arr[t] += v;
        __syncthreads();
    }
    if (t < NWIN) win_base[t] = arr[t] - own;
    if (t == NWIN - 1) win_base[NWIN] = arr[t];
}

// per-(block,window) start offsets: block_off[b][w]
__global__ __launch_bounds__(64) void k_scan2(const int* __restrict__ block_counts,
                                              const int* __restrict__ win_base,
                                              int* __restrict__ block_off) {
    int w = blockIdx.x, lane = threadIdx.x;
    int c[4];
    int lsum = 0;
    #pragma unroll
    for (int i = 0; i < 4; i++) {
        c[i] = block_counts[(lane * 4 + i) * NWIN + w];
        lsum += c[i];
    }
    int incl = lsum;
    #pragma unroll
    for (int off = 1; off < 64; off <<= 1) {
        int u = __shfl_up(incl, off, 64);
        if (lane >= off) incl += u;
    }
    int run = win_base[w] + incl - lsum;
    #pragma unroll
    for (int i = 0; i < 4; i++) {
        block_off[(lane * 4 + i) * NWIN + w] = run;
        run += c[i];
    }
}

// distribute edges into window-grouped buffers (dense coalesced writes,
// LDS atomics only)
__global__ __launch_bounds__(256) void k_scatter(const int* __restrict__ src,
                                                 const int* __restrict__ dst,
                                                 const float* __restrict__ ew,
                                                 const int* __restrict__ block_off,
                                                 int2* __restrict__ esw,
                                                 int* __restrict__ edst) {
    __shared__ int myoff[NWIN];
    int t = threadIdx.x, b = blockIdx.x;
    for (int i = t; i < NWIN; i += 256) myoff[i] = block_off[b * NWIN + i];
    __syncthreads();
    int e0 = b * CHUNK;
    for (int e = e0 + t; e < e0 + CHUNK; e += 256) {
        int d = dst[e];
        int w = d >> WSHIFT;
        int pos = atomicAdd(&myoff[w], 1);
        esw[pos]  = make_int2(src[e], __float_as_int(ew[e]));
        edst[pos] = d;
    }
}

// one block per window: fill buckets with LDS counters; writes confined to a
// 256 KB L2-resident, temporally-clustered region. Zero device atomics.
__global__ __launch_bounds__(256) void k_fill2(const int* __restrict__ win_base,
                                               const int2* __restrict__ esw,
                                               const int* __restrict__ edst,
                                               int2* __restrict__ pairs,
                                               int* __restrict__ cnt) {
    __shared__ int cnt_l[512];
    int t = threadIdx.x, w = blockIdx.x;
    for (int i = t; i < 512; i += 256) cnt_l[i] = 0;
    __syncthreads();
    int e0 = win_base[w], e1 = win_base[w + 1];
    for (int e = e0 + t; e < e1; e += 256) {
        int d = edst[e];
        int pos = atomicAdd(&cnt_l[d - (w << WSHIFT)], 1);
        if (pos < CAP) pairs[(size_t)d * CAP + pos] = esw[e];
    }
    __syncthreads();
    for (int i = t; i < 512; i += 256) {
        int node = (w << WSHIFT) + i;
        if (node < NNODES) cnt[node] = cnt_l[i] < CAP ? cnt_l[i] : CAP;
    }
}

// ---------------- degree + normalization ----------------

// wave per node: deg = sum of bucket weights (coalesced, no atomics),
// dinv = rsqrt(deg+1), self_norm = dinv^2.
__global__ __launch_bounds__(256) void k_degsum(const int* __restrict__ cnt,
                                                const int2* __restrict__ pairs,
                                                float* __restrict__ dinv,
                                                float* __restrict__ self_norm) {
    int t = threadIdx.x, lane = t & 63;
    int n = blockIdx.x * 4 + (t >> 6);
    if (n >= NNODES) return;
    int cn = cnt[n];
    int2 pr = pairs[(size_t)n * CAP + lane];
    float s = (lane < cn) ? __int_as_float(pr.y) : 0.0f;
    for (int off = 32; off > 0; off >>= 1) s += __shfl_down(s, off, 64);
    if (lane == 0) {
        float dv = rsqrtf(s + 1.0f);
        dinv[n] = dv;
        self_norm[n] = dv * dv;
    }
}

// wave per node: normalize bucket weights (w *= dinv[s]*dinv[d]) and pad the
// bucket to a multiple of 16 with (n, 0.0f) dummies. Coalesced 8 B/lane.
__global__ __launch_bounds__(256) void k_norm(const float* __restrict__ dinv,
                                              const int* __restrict__ cnt,
                                              int2* __restrict__ pairs) {
    int t = threadIdx.x, lane = t & 63;
    int n = blockIdx.x * 4 + (t >> 6);
    if (n >= NNODES) return;
    int cn = cnt[n];
    int c16 = (cn + 15) & ~15;
    float dd = dinv[n];
    if (lane < c16) {
        int2 outp;
        if (lane < cn) {
            int2 pr = pairs[(size_t)n * CAP + lane];
            float w = __int_as_float(pr.y) * dd * dinv[pr.x];
            outp = make_int2(pr.x, __float_as_int(w));
        } else {
            outp = make_int2(n, 0);   // weight bits 0 == 0.0f
        }
        pairs[(size_t)n * CAP + lane] = outp;
    }
}

// ---------------- GEMM: [200000 x 64] @ [64 x 64] -> fp16 ----------------

template <bool TR>
__global__ __launch_bounds__(256) void k_gemm(const void* __restrict__ Xv,
                                              const float* __restrict__ Wg,
                                              __half* __restrict__ Y,
                                              const float* __restrict__ Acoef,
                                              const float* __restrict__ Bcoef) {
    __shared__ __align__(16) float Wl[64 * 64];
    int t = threadIdx.x;
    #pragma unroll
    for (int i = 0; i < 16; i++) Wl[i * 256 + t] = Wg[i * 256 + t];
    __syncthreads();

    int wid  = blockIdx.x * 4 + (t >> 6);
    int lane = t & 63;
    int c = wid & 1;
    int g = wid >> 1;
    int n = g * 64 + lane;
    if (n >= NNODES) return;
    int row = n * 2 + c;

    float4 xr[16];
    if constexpr (!TR) {
        const float* xp = (const float*)Xv + (size_t)row * 64;
        #pragma unroll
        for (int q = 0; q < 16; q++) xr[q] = ((const float4*)xp)[q];
    } else {
        const __half* xp = (const __half*)Xv + (size_t)row * 64;
        #pragma unroll
        for (int q = 0; q < 8; q++) {
            uint4 u = ((const uint4*)xp)[q];
            float2 a = __half22float2(*(const __half2*)&u.x);
            float2 b = __half22float2(*(const __half2*)&u.y);
            float2 cc = __half22float2(*(const __half2*)&u.z);
            float2 d = __half22float2(*(const __half2*)&u.w);
            xr[2 * q]     = make_float4(a.x, a.y, b.x, b.y);
            xr[2 * q + 1] = make_float4(cc.x, cc.y, d.x, d.y);
        }
        const float* A = Acoef + c * 64;
        const float* B = Bcoef + c * 64;
        #pragma unroll
        for (int q = 0; q < 16; q++) {
            float4 a = ((const float4*)A)[q];
            float4 b = ((const float4*)B)[q];
            xr[q].x = fmaxf(a.x * xr[q].x + b.x, 0.0f);
            xr[q].y = fmaxf(a.y * xr[q].y + b.y, 0.0f);
            xr[q].z = fmaxf(a.z * xr[q].z + b.z, 0.0f);
            xr[q].w = fmaxf(a.w * xr[q].w + b.w, 0.0f);
        }
    }

    __half* yp = Y + (size_t)row * 64;
    for (int jg = 0; jg < 16; jg++) {
        float4 acc = make_float4(0.f, 0.f, 0.f, 0.f);
        const float* xs = (const float*)xr;
        #pragma unroll
        for (int k = 0; k < 64; k++) {
            float xv = xs[k];
            float4 w4 = ((const float4*)(Wl + k * 64))[jg];
            acc.x += xv * w4.x; acc.y += xv * w4.y;
            acc.z += xv * w4.z; acc.w += xv * w4.w;
        }
        union { __half2 h2[2]; uint2 u2; } cv;
        cv.h2[0] = __floats2half2_rn(acc.x, acc.y);
        cv.h2[1] = __floats2half2_rn(acc.z, acc.w);
        ((uint2*)yp)[jg] = cv.u2;
    }
}

// ---------------- pull-style GCN aggregation (fp16 in, fp16 out) -----------

__global__ __launch_bounds__(256) void k_prop(const __half* __restrict__ hw,
                                              const float* __restrict__ bias,
                                              const float* __restrict__ self_norm,
                                              const int* __restrict__ cnt,
                                              const int2* __restrict__ pairs,
                                              __half* __restrict__ agg) {
    int t = threadIdx.x;
    int lane = t & 63;
    int n = __builtin_amdgcn_readfirstlane(blockIdx.x * 4 + (t >> 6));
    if (n >= NNODES) return;

    int f = lane * 2;            // flat half-offset in [0,128), even
    int feat = f & 63;

    float2 bv = *(const float2*)(bias + feat);
    float sn = self_norm[n];
    float2 self = __half22float2(*(const __half2*)(hw + (size_t)n * 128 + f));
    float acc0 = bv.x + sn * self.x;
    float acc1 = bv.y + sn * self.y;

    int cn = cnt[n];
    int c16 = (cn + 15) & ~15;
    const unsigned long long* pp = (const unsigned long long*)(pairs + (size_t)n * CAP);

    for (int p = 0; p < c16; p += 16) {
        const unsigned long long* q = pp + p;
        unsigned long long e[16];
        #pragma unroll
        for (int i = 0; i < 16; i++) e[i] = __builtin_nontemporal_load(q + i);
        float2 h[16];
        #pragma unroll
        for (int i = 0; i < 16; i++) {
            int s = (int)(e[i] & 0xffffffffu);
            h[i] = __half22float2(*(const __half2*)(hw + (size_t)s * 128 + f));
        }
        #pragma unroll
        for (int i = 0; i < 16; i++) {
            float w = __int_as_float((int)(e[i] >> 32));
            acc0 += w * h[i].x;
            acc1 += w * h[i].y;
        }
    }

    *(__half2*)(agg + (size_t)n * 128 + f) = __floats2half2_rn(acc0, acc1);
}

// ---------------- GraphNorm stats (sum, sumsq per column) ----------------

__global__ __launch_bounds__(256) void k_stats(const __half* __restrict__ agg,
                                               float* __restrict__ stats) {
    int t = threadIdx.x;
    int col = (t & 63) * 2;
    int rg  = t >> 6;
    float s0 = 0.f, s1 = 0.f, q0 = 0.f, q1 = 0.f;
    for (int r = blockIdx.x * 4 + rg; r < NNODES; r += gridDim.x * 4) {
        float2 v = __half22float2(*(const __half2*)(agg + (size_t)r * 128 + col));
        s0 += v.x; s1 += v.y; q0 += v.x * v.x; q1 += v.y * v.y;
    }
    atomicAdd(&stats[col], s0);       atomicAdd(&stats[col + 1], s1);
    atomicAdd(&stats[128 + col], q0); atomicAdd(&stats[128 + col + 1], q1);
}

__global__ void k_coef(float* stats, const float* __restrict__ gn_w,
                       const float* __restrict__ gn_b, const float* __restrict__ gn_ms) {
    int col = threadIdx.x;  // 128
    float inv_n = 1.0f / (float)NNODES;
    float mean = stats[col] * inv_n;
    float eh2  = stats[128 + col] * inv_n;
    int f = col & 63;
    float ms = gn_ms[f];
    float var = eh2 - 2.0f * ms * mean * mean + ms * ms * mean * mean;
    float A = gn_w[f] * rsqrtf(var + 1e-5f);
    stats[256 + col] = A;
    stats[384 + col] = gn_b[f] - A * ms * mean;
}

// ---------------- fused subgraph pooling + MLP head ----------------

__global__ __launch_bounds__(128) void k_head(const __half* __restrict__ agg,
                                              const int* __restrict__ subg,
                                              const float* __restrict__ mW1,
                                              const float* __restrict__ mb1,
                                              const float* __restrict__ mW2,
                                              const float* __restrict__ mb2,
                                              float* __restrict__ out) {
    __shared__ float pl[128];
    __shared__ float red[128];
    int s = blockIdx.x, t = threadIdx.x;
    int j = t & 63, half = t >> 6;
    const int* idx = subg + s * 64;
    float acc = 0.f;
    for (int m = half * 32; m < half * 32 + 32; m++) {
        int n = idx[m];
        acc += 0.5f * (__half2float(agg[(size_t)n * 128 + j]) +
                       __half2float(agg[(size_t)n * 128 + 64 + j]));
    }
    pl[half * 64 + j] = acc;
    __syncthreads();
    if (t < 64) pl[t] += pl[64 + t];
    __syncthreads();
    float h = mb1[t];
    #pragma unroll
    for (int k = 0; k < 64; k++) h += pl[k] * mW1[k * 128 + t];
    h = fmaxf(h, 0.0f);
    red[t] = h * mW2[t];
    __syncthreads();
    for (int off = 64; off > 0; off >>= 1) {
        if (t < off) red[t] += red[t + off];
        __syncthreads();
    }
    if (t == 0) out[s] = red[0] + mb2[0];
}

// ---------------- launcher ----------------

extern "C" void kernel_launch(void* const* d_in, const int* in_sizes, int n_in,
                              void* d_out, int out_size, void* d_ws, size_t ws_size,
                              hipStream_t stream) {
    const float* x     = (const float*)d_in[0];
    const int*   ei    = (const int*)d_in[1];
    const float* ew    = (const float*)d_in[2];
    const int*   subg  = (const int*)d_in[3];
    const float* W1    = (const float*)d_in[4];
    const float* b1    = (const float*)d_in[5];
    const float* gn_w  = (const float*)d_in[6];
    const float* gn_b  = (const float*)d_in[7];
    const float* gn_ms = (const float*)d_in[8];
    const float* W2    = (const float*)d_in[9];
    const float* b2    = (const float*)d_in[10];
    const float* mW1   = (const float*)d_in[11];
    const float* mb1   = (const float*)d_in[12];
    const float* mW2   = (const float*)d_in[13];
    const float* mb2   = (const float*)d_in[14];
    float* out = (float*)d_out;

    char* w = (char*)d_ws;
    size_t off = 0;
    auto alloc = [&](size_t bytes) {
        void* p = w + off;
        off = (off + bytes + 255) & ~(size_t)255;
        return p;
    };
    float*  dinv      = (float*) alloc((size_t)NNODES * 4);
    float*  self_norm = (float*) alloc((size_t)NNODES * 4);
    int*    cnt       = (int*)   alloc((size_t)NNODES * 4);
    int2*   pairs     = (int2*)  alloc((size_t)NNODES * CAP * 8);  // 51.2 MB
    __half* hw        = (__half*)alloc((size_t)NNODES * 128 * 2);  // 25.6 MB
    __half* agg       = (__half*)alloc((size_t)NNODES * 128 * 2);  // 25.6 MB
    float*  stats     = (float*) alloc(512 * 4);
    int*    block_counts = (int*)alloc((size_t)NBLK * NWIN * 4);   // 200 KB
    int*    block_off    = (int*)alloc((size_t)NBLK * NWIN * 4);   // 200 KB
    int*    win_base     = (int*)alloc((NWIN + 1) * 4);
    int2*   esw          = (int2*)alloc((size_t)NEDGES * 8);       // 12.8 MB
    int*    edst         = (int*) alloc((size_t)NEDGES * 4);       // 6.4 MB

    const int* src = ei;
    const int* dst = ei + NEDGES;

    hipMemsetAsync(stats, 0, 512 * 4, stream);

    // edge binning (counting sort by 512-node dst window) + bucket fill
    k_hist   <<<NBLK, 256, 0, stream>>>(dst, block_counts);
    k_scan1  <<<1, 256, 0, stream>>>(block_counts, win_base);
    k_scan2  <<<NWIN, 64, 0, stream>>>(block_counts, win_base, block_off);
    k_scatter<<<NBLK, 256, 0, stream>>>(src, dst, ew, block_off, esw, edst);
    k_fill2  <<<NWIN, 256, 0, stream>>>(win_base, esw, edst, pairs, cnt);

    // degrees + weight normalization + padding
    k_degsum<<<25000, 256, 0, stream>>>(cnt, pairs, dinv, self_norm);
    k_norm  <<<25000, 256, 0, stream>>>(dinv, cnt, pairs);

    // layer 1
    k_gemm<false><<<782, 256, 0, stream>>>(x, W1, hw, nullptr, nullptr);
    k_prop<<<25000, 256, 0, stream>>>(hw, b1, self_norm, cnt, pairs, agg);

    // GraphNorm coefficients
    k_stats<<<256, 256, 0, stream>>>(agg, stats);
    k_coef<<<1, 128, 0, stream>>>(stats, gn_w, gn_b, gn_ms);

    // layer 2 (GraphNorm+ReLU fused into GEMM2 input)
    k_gemm<true><<<782, 256, 0, stream>>>(agg, W2, hw, stats + 256, stats + 384);
    k_prop<<<25000, 256, 0, stream>>>(hw, b2, self_norm, cnt, pairs, agg);

    // fused pooling + MLP head
    k_head<<<NSUB, 128, 0, stream>>>(agg, subg, mW1, mb1, mW2, mb2, out);
}

// Round 6
// 453.260 us; speedup vs baseline: 1.3622x; 1.1579x over previous
//
#include <hip/hip_runtime.h>
#include <hip/hip_fp16.h>

#define NNODES 100000
#define NEDGES 1600000
#define NSUB   1000
#define MSUB   64
#define MHID   128
#define CAP    64     // max in-degree bucket capacity (Poisson(16): P(>=64) ~ 1e-20)

#define WSHIFT 9                         // 512-node dst windows
#define NWIN   ((NNODES + 511) >> 9)     // 196
#define NBLK   256                       // blocks for hist/scatter
#define CHUNK  (NEDGES / NBLK)           // 6250 exact

// ---------------- edge binning: counting sort by dst window ----------------

__global__ __launch_bounds__(256) void k_hist(const int* __restrict__ dst,
                                              int* __restrict__ block_counts) {
    __shared__ int hist[NWIN];
    int t = threadIdx.x, b = blockIdx.x;
    for (int i = t; i < NWIN; i += 256) hist[i] = 0;
    __syncthreads();
    int e0 = b * CHUNK;
    for (int e = e0 + t; e < e0 + CHUNK; e += 256)
        atomicAdd(&hist[dst[e] >> WSHIFT], 1);
    __syncthreads();
    for (int i = t; i < NWIN; i += 256) block_counts[b * NWIN + i] = hist[i];
}

__global__ __launch_bounds__(256) void k_scan1(const int* __restrict__ block_counts,
                                               int* __restrict__ win_base) {
    __shared__ int arr[256];
    int t = threadIdx.x;
    int own = 0;
    if (t < NWIN) for (int b = 0; b < NBLK; b++) own += block_counts[b * NWIN + t];
    arr[t] = own;
    __syncthreads();
    for (int off = 1; off < 256; off <<= 1) {
        int v = (t >= off) ? arr[t - off] : 0;
        __syncthreads();
        arr[t] += v;
        __syncthreads();
    }
    if (t < NWIN) win_base[t] = arr[t] - own;
    if (t == NWIN - 1) win_base[NWIN] = arr[t];
}

__global__ __launch_bounds__(64) void k_scan2(const int* __restrict__ block_counts,
                                              const int* __restrict__ win_base,
                                              int* __restrict__ block_off) {
    int w = blockIdx.x, lane = threadIdx.x;
    int c[4];
    int lsum = 0;
    #pragma unroll
    for (int i = 0; i < 4; i++) {
        c[i] = block_counts[(lane * 4 + i) * NWIN + w];
        lsum += c[i];
    }
    int incl = lsum;
    #pragma unroll
    for (int off = 1; off < 64; off <<= 1) {
        int u = __shfl_up(incl, off, 64);
        if (lane >= off) incl += u;
    }
    int run = win_base[w] + incl - lsum;
    #pragma unroll
    for (int i = 0; i < 4; i++) {
        block_off[(lane * 4 + i) * NWIN + w] = run;
        run += c[i];
    }
}

__global__ __launch_bounds__(256) void k_scatter(const int* __restrict__ src,
                                                 const int* __restrict__ dst,
                                                 const float* __restrict__ ew,
                                                 const int* __restrict__ block_off,
                                                 int2* __restrict__ esw,
                                                 int* __restrict__ edst) {
    __shared__ int myoff[NWIN];
    int t = threadIdx.x, b = blockIdx.x;
    for (int i = t; i < NWIN; i += 256) myoff[i] = block_off[b * NWIN + i];
    __syncthreads();
    int e0 = b * CHUNK;
    for (int e = e0 + t; e < e0 + CHUNK; e += 256) {
        int d = dst[e];
        int w = d >> WSHIFT;
        int pos = atomicAdd(&myoff[w], 1);
        esw[pos]  = make_int2(src[e], __float_as_int(ew[e]));
        edst[pos] = d;
    }
}

// one block per window: fill buckets (raw edge weights) with LDS counters.
__global__ __launch_bounds__(256) void k_fill2(const int* __restrict__ win_base,
                                               const int2* __restrict__ esw,
                                               const int* __restrict__ edst,
                                               int2* __restrict__ pairs,
                                               int* __restrict__ cnt) {
    __shared__ int cnt_l[512];
    int t = threadIdx.x, w = blockIdx.x;
    for (int i = t; i < 512; i += 256) cnt_l[i] = 0;
    __syncthreads();
    int e0 = win_base[w], e1 = win_base[w + 1];
    for (int e = e0 + t; e < e1; e += 256) {
        int d = edst[e];
        int pos = atomicAdd(&cnt_l[d - (w << WSHIFT)], 1);
        if (pos < CAP) pairs[(size_t)d * CAP + pos] = esw[e];
    }
    __syncthreads();
    for (int i = t; i < 512; i += 256) {
        int node = (w << WSHIFT) + i;
        if (node < NNODES) cnt[node] = cnt_l[i] < CAP ? cnt_l[i] : CAP;
    }
}

// ---------------- degree (raw weight sum) + bucket padding, one pass --------
// wave per node: dinv[n] = rsqrt(sum(w)+1); pad bucket to multiple of 16 with
// (n, 0.0f) dummies. All coalesced, no device atomics.

__global__ __launch_bounds__(256) void k_degpad(const int* __restrict__ cnt,
                                                int2* __restrict__ pairs,
                                                float* __restrict__ dinv) {
    int t = threadIdx.x, lane = t & 63;
    int n = blockIdx.x * 4 + (t >> 6);
    if (n >= NNODES) return;
    int cn = cnt[n];
    int2 pr = pairs[(size_t)n * CAP + lane];
    float s = (lane < cn) ? __int_as_float(pr.y) : 0.0f;
    for (int off = 32; off > 0; off >>= 1) s += __shfl_down(s, off, 64);
    if (lane == 0) dinv[n] = rsqrtf(s + 1.0f);
    int c16 = (cn + 15) & ~15;
    if (lane >= cn && lane < c16)
        pairs[(size_t)n * CAP + lane] = make_int2(n, 0);   // weight bits 0 == 0.0f
}

// ---------------- GEMM: [200000 x 64] @ [64 x 64] -> fp16, row-scaled -------
// Writes hw'[n] = dinv[n] * (x[n] @ W). TR=true: fp16 input with fused
// GraphNorm affine + ReLU.

template <bool TR>
__global__ __launch_bounds__(256) void k_gemm(const void* __restrict__ Xv,
                                              const float* __restrict__ Wg,
                                              const float* __restrict__ dinv,
                                              __half* __restrict__ Y,
                                              const float* __restrict__ Acoef,
                                              const float* __restrict__ Bcoef) {
    __shared__ __align__(16) float Wl[64 * 64];
    int t = threadIdx.x;
    #pragma unroll
    for (int i = 0; i < 16; i++) Wl[i * 256 + t] = Wg[i * 256 + t];
    __syncthreads();

    int wid  = blockIdx.x * 4 + (t >> 6);
    int lane = t & 63;
    int c = wid & 1;
    int g = wid >> 1;
    int n = g * 64 + lane;
    if (n >= NNODES) return;
    int row = n * 2 + c;
    float dv = dinv[n];

    float4 xr[16];
    if constexpr (!TR) {
        const float* xp = (const float*)Xv + (size_t)row * 64;
        #pragma unroll
        for (int q = 0; q < 16; q++) xr[q] = ((const float4*)xp)[q];
    } else {
        const __half* xp = (const __half*)Xv + (size_t)row * 64;
        #pragma unroll
        for (int q = 0; q < 8; q++) {
            uint4 u = ((const uint4*)xp)[q];
            float2 a = __half22float2(*(const __half2*)&u.x);
            float2 b = __half22float2(*(const __half2*)&u.y);
            float2 cc = __half22float2(*(const __half2*)&u.z);
            float2 d = __half22float2(*(const __half2*)&u.w);
            xr[2 * q]     = make_float4(a.x, a.y, b.x, b.y);
            xr[2 * q + 1] = make_float4(cc.x, cc.y, d.x, d.y);
        }
        const float* A = Acoef + c * 64;
        const float* B = Bcoef + c * 64;
        #pragma unroll
        for (int q = 0; q < 16; q++) {
            float4 a = ((const float4*)A)[q];
            float4 b = ((const float4*)B)[q];
            xr[q].x = fmaxf(a.x * xr[q].x + b.x, 0.0f);
            xr[q].y = fmaxf(a.y * xr[q].y + b.y, 0.0f);
            xr[q].z = fmaxf(a.z * xr[q].z + b.z, 0.0f);
            xr[q].w = fmaxf(a.w * xr[q].w + b.w, 0.0f);
        }
    }

    __half* yp = Y + (size_t)row * 64;
    for (int jg = 0; jg < 16; jg++) {
        float4 acc = make_float4(0.f, 0.f, 0.f, 0.f);
        const float* xs = (const float*)xr;
        #pragma unroll
        for (int k = 0; k < 64; k++) {
            float xv = xs[k];
            float4 w4 = ((const float4*)(Wl + k * 64))[jg];
            acc.x += xv * w4.x; acc.y += xv * w4.y;
            acc.z += xv * w4.z; acc.w += xv * w4.w;
        }
        union { __half2 h2[2]; uint2 u2; } cv;
        cv.h2[0] = __floats2half2_rn(acc.x * dv, acc.y * dv);
        cv.h2[1] = __floats2half2_rn(acc.z * dv, acc.w * dv);
        ((uint2*)yp)[jg] = cv.u2;
    }
}

// ---------------- pull-style GCN aggregation (fp16 in, fp16 out) -----------
// agg[n] = dinv[n] * (hw'[n] + sum_e ew_e * hw'[src_e]) + bias

__global__ __launch_bounds__(256) void k_prop(const __half* __restrict__ hw,
                                              const float* __restrict__ bias,
                                              const float* __restrict__ dinv,
                                              const int* __restrict__ cnt,
                                              const int2* __restrict__ pairs,
                                              __half* __restrict__ agg) {
    int t = threadIdx.x;
    int lane = t & 63;
    int n = __builtin_amdgcn_readfirstlane(blockIdx.x * 4 + (t >> 6));
    if (n >= NNODES) return;

    int f = lane * 2;            // flat half-offset in [0,128), even
    int feat = f & 63;

    float2 bv = *(const float2*)(bias + feat);
    float dv = dinv[n];
    float2 self = __half22float2(*(const __half2*)(hw + (size_t)n * 128 + f));
    float acc0 = self.x;
    float acc1 = self.y;

    int cn = cnt[n];
    int c16 = (cn + 15) & ~15;
    const unsigned long long* pp = (const unsigned long long*)(pairs + (size_t)n * CAP);

    for (int p = 0; p < c16; p += 16) {
        const unsigned long long* q = pp + p;
        unsigned long long e[16];
        #pragma unroll
        for (int i = 0; i < 16; i++) e[i] = __builtin_nontemporal_load(q + i);
        float2 h[16];
        #pragma unroll
        for (int i = 0; i < 16; i++) {
            int s = (int)(e[i] & 0xffffffffu);
            h[i] = __half22float2(*(const __half2*)(hw + (size_t)s * 128 + f));
        }
        #pragma unroll
        for (int i = 0; i < 16; i++) {
            float w = __int_as_float((int)(e[i] >> 32));
            acc0 += w * h[i].x;
            acc1 += w * h[i].y;
        }
    }

    *(__half2*)(agg + (size_t)n * 128 + f) =
        __floats2half2_rn(dv * acc0 + bv.x, dv * acc1 + bv.y);
}

// ---------------- GraphNorm stats (sum, sumsq per column) ----------------
// 512 blocks; thread handles 8 consecutive columns via one uint4 load per row.

__global__ __launch_bounds__(256) void k_stats(const __half* __restrict__ agg,
                                               float* __restrict__ stats) {
    __shared__ float ls[16][128];
    __shared__ float lq[16][128];
    int t = threadIdx.x;
    int cb = (t & 15) * 8;      // column base
    int rg = t >> 4;            // row group within block (16 rows/iter)
    float s[8], q[8];
    #pragma unroll
    for (int i = 0; i < 8; i++) { s[i] = 0.f; q[i] = 0.f; }
    for (int r = blockIdx.x * 16 + rg; r < NNODES; r += gridDim.x * 16) {
        uint4 u = *(const uint4*)(agg + (size_t)r * 128 + cb);
        const __half2* h2 = (const __half2*)&u;
        #pragma unroll
        for (int i = 0; i < 4; i++) {
            float2 v = __half22float2(h2[i]);
            s[2*i]   += v.x; q[2*i]   += v.x * v.x;
            s[2*i+1] += v.y; q[2*i+1] += v.y * v.y;
        }
    }
    #pragma unroll
    for (int i = 0; i < 8; i++) { ls[rg][cb + i] = s[i]; lq[rg][cb + i] = q[i]; }
    __syncthreads();
    if (t < 128) {
        float a = 0.f, b = 0.f;
        #pragma unroll
        for (int g = 0; g < 16; g++) { a += ls[g][t]; b += lq[g][t]; }
        atomicAdd(&stats[t], a);
        atomicAdd(&stats[128 + t], b);
    }
}

__global__ void k_coef(float* stats, const float* __restrict__ gn_w,
                       const float* __restrict__ gn_b, const float* __restrict__ gn_ms) {
    int col = threadIdx.x;  // 128
    float inv_n = 1.0f / (float)NNODES;
    float mean = stats[col] * inv_n;
    float eh2  = stats[128 + col] * inv_n;
    int f = col & 63;
    float ms = gn_ms[f];
    float var = eh2 - 2.0f * ms * mean * mean + ms * ms * mean * mean;
    float A = gn_w[f] * rsqrtf(var + 1e-5f);
    stats[256 + col] = A;
    stats[384 + col] = gn_b[f] - A * ms * mean;
}

// ---------------- fused subgraph pooling + MLP head ----------------

__global__ __launch_bounds__(128) void k_head(const __half* __restrict__ agg,
                                              const int* __restrict__ subg,
                                              const float* __restrict__ mW1,
                                              const float* __restrict__ mb1,
                                              const float* __restrict__ mW2,
                                              const float* __restrict__ mb2,
                                              float* __restrict__ out) {
    __shared__ float pl[128];
    __shared__ float red[128];
    int s = blockIdx.x, t = threadIdx.x;
    int j = t & 63, half = t >> 6;
    const int* idx = subg + s * 64;
    float acc = 0.f;
    for (int m = half * 32; m < half * 32 + 32; m++) {
        int n = idx[m];
        acc += 0.5f * (__half2float(agg[(size_t)n * 128 + j]) +
                       __half2float(agg[(size_t)n * 128 + 64 + j]));
    }
    pl[half * 64 + j] = acc;
    __syncthreads();
    if (t < 64) pl[t] += pl[64 + t];
    __syncthreads();
    float h = mb1[t];
    #pragma unroll
    for (int k = 0; k < 64; k++) h += pl[k] * mW1[k * 128 + t];
    h = fmaxf(h, 0.0f);
    red[t] = h * mW2[t];
    __syncthreads();
    for (int off = 64; off > 0; off >>= 1) {
        if (t < off) red[t] += red[t + off];
        __syncthreads();
    }
    if (t == 0) out[s] = red[0] + mb2[0];
}

// ---------------- launcher ----------------

extern "C" void kernel_launch(void* const* d_in, const int* in_sizes, int n_in,
                              void* d_out, int out_size, void* d_ws, size_t ws_size,
                              hipStream_t stream) {
    const float* x     = (const float*)d_in[0];
    const int*   ei    = (const int*)d_in[1];
    const float* ew    = (const float*)d_in[2];
    const int*   subg  = (const int*)d_in[3];
    const float* W1    = (const float*)d_in[4];
    const float* b1    = (const float*)d_in[5];
    const float* gn_w  = (const float*)d_in[6];
    const float* gn_b  = (const float*)d_in[7];
    const float* gn_ms = (const float*)d_in[8];
    const float* W2    = (const float*)d_in[9];
    const float* b2    = (const float*)d_in[10];
    const float* mW1   = (const float*)d_in[11];
    const float* mb1   = (const float*)d_in[12];
    const float* mW2   = (const float*)d_in[13];
    const float* mb2   = (const float*)d_in[14];
    float* out = (float*)d_out;

    char* w = (char*)d_ws;
    size_t off = 0;
    auto alloc = [&](size_t bytes) {
        void* p = w + off;
        off = (off + bytes + 255) & ~(size_t)255;
        return p;
    };
    float*  dinv      = (float*) alloc((size_t)NNODES * 4);
    int*    cnt       = (int*)   alloc((size_t)NNODES * 4);
    int2*   pairs     = (int2*)  alloc((size_t)NNODES * CAP * 8);  // 51.2 MB
    __half* hw        = (__half*)alloc((size_t)NNODES * 128 * 2);  // 25.6 MB
    __half* agg       = (__half*)alloc((size_t)NNODES * 128 * 2);  // 25.6 MB
    float*  stats     = (float*) alloc(512 * 4);
    int*    block_counts = (int*)alloc((size_t)NBLK * NWIN * 4);   // 200 KB
    int*    block_off    = (int*)alloc((size_t)NBLK * NWIN * 4);   // 200 KB
    int*    win_base     = (int*)alloc((NWIN + 1) * 4);
    int2*   esw          = (int2*)alloc((size_t)NEDGES * 8);       // 12.8 MB
    int*    edst         = (int*) alloc((size_t)NEDGES * 4);       // 6.4 MB

    const int* src = ei;
    const int* dst = ei + NEDGES;

    hipMemsetAsync(stats, 0, 512 * 4, stream);

    // edge binning (counting sort by 512-node dst window) + bucket fill
    k_hist   <<<NBLK, 256, 0, stream>>>(dst, block_counts);
    k_scan1  <<<1, 256, 0, stream>>>(block_counts, win_base);
    k_scan2  <<<NWIN, 64, 0, stream>>>(block_counts, win_base, block_off);
    k_scatter<<<NBLK, 256, 0, stream>>>(src, dst, ew, block_off, esw, edst);
    k_fill2  <<<NWIN, 256, 0, stream>>>(win_base, esw, edst, pairs, cnt);

    // degrees + padding (raw weights kept; dinv folded into GEMM epilogue)
    k_degpad<<<25000, 256, 0, stream>>>(cnt, pairs, dinv);

    // layer 1
    k_gemm<false><<<782, 256, 0, stream>>>(x, W1, dinv, hw, nullptr, nullptr);
    k_prop<<<25000, 256, 0, stream>>>(hw, b1, dinv, cnt, pairs, agg);

    // GraphNorm coefficients
    k_stats<<<512, 256, 0, stream>>>(agg, stats);
    k_coef<<<1, 128, 0, stream>>>(stats, gn_w, gn_b, gn_ms);

    // layer 2 (GraphNorm+ReLU fused into GEMM2 input)
    k_gemm<true><<<782, 256, 0, stream>>>(agg, W2, dinv, hw, stats + 256, stats + 384);
    k_prop<<<25000, 256, 0, stream>>>(hw, b2, dinv, cnt, pairs, agg);

    // fused pooling + MLP head
    k_head<<<NSUB, 128, 0, stream>>>(agg, subg, mW1, mb1, mW2, mb2, out);
}

// Round 7
// 416.530 us; speedup vs baseline: 1.4823x; 1.0882x over previous
//
#include <hip/hip_runtime.h>
#include <hip/hip_fp16.h>

#define NNODES 100000
#define NEDGES 1600000
#define NSUB   1000
#define MSUB   64
#define MHID   128

#define WSHIFT 9                         // 512-node dst windows
#define WIN    512
#define NWIN   ((NNODES + 511) >> 9)     // 196
#define NBLK   256                       // blocks for hist/scatter
#define CHUNK  (NEDGES / NBLK)           // 6250 exact

// ---------------- edge binning: counting sort by dst window ----------------

__global__ __launch_bounds__(256) void k_hist(const int* __restrict__ dst,
                                              int* __restrict__ block_counts) {
    __shared__ int hist[NWIN];
    int t = threadIdx.x, b = blockIdx.x;
    for (int i = t; i < NWIN; i += 256) hist[i] = 0;
    __syncthreads();
    int e0 = b * CHUNK;
    for (int e = e0 + t; e < e0 + CHUNK; e += 256)
        atomicAdd(&hist[dst[e] >> WSHIFT], 1);
    __syncthreads();
    for (int i = t; i < NWIN; i += 256) block_counts[b * NWIN + i] = hist[i];
}

// per-window totals: block w sums column w over 256 blocks (parallel, replaces
// the serial 1-block scan1 reduction)
__global__ __launch_bounds__(256) void k_winsum(const int* __restrict__ block_counts,
                                                int* __restrict__ win_total) {
    __shared__ int red[256];
    int t = threadIdx.x, w = blockIdx.x;
    red[t] = block_counts[t * NWIN + w];
    __syncthreads();
    for (int off = 128; off > 0; off >>= 1) {
        if (t < off) red[t] += red[t + off];
        __syncthreads();
    }
    if (t == 0) win_total[w] = red[0];
}

// tiny: exclusive scan of 196 window totals; also zero the stats block
__global__ __launch_bounds__(256) void k_scan(const int* __restrict__ win_total,
                                              int* __restrict__ win_base,
                                              float* __restrict__ stats) {
    __shared__ int arr[256];
    int t = threadIdx.x;
    int own = (t < NWIN) ? win_total[t] : 0;
    arr[t] = own;
    __syncthreads();
    for (int off = 1; off < 256; off <<= 1) {
        int v = (t >= off) ? arr[t - off] : 0;
        __syncthreads();
        arr[t] += v;
        __syncthreads();
    }
    if (t < NWIN) win_base[t] = arr[t] - own;
    if (t == NWIN - 1) win_base[NWIN] = arr[t];
    stats[t] = 0.0f; stats[t + 256] = 0.0f;
}

__global__ __launch_bounds__(64) void k_scan2(const int* __restrict__ block_counts,
                                              const int* __restrict__ win_base,
                                              int* __restrict__ block_off) {
    int w = blockIdx.x, lane = threadIdx.x;
    int c[4];
    int lsum = 0;
    #pragma unroll
    for (int i = 0; i < 4; i++) {
        c[i] = block_counts[(lane * 4 + i) * NWIN + w];
        lsum += c[i];
    }
    int incl = lsum;
    #pragma unroll
    for (int off = 1; off < 64; off <<= 1) {
        int u = __shfl_up(incl, off, 64);
        if (lane >= off) incl += u;
    }
    int run = win_base[w] + incl - lsum;
    #pragma unroll
    for (int i = 0; i < 4; i++) {
        block_off[(lane * 4 + i) * NWIN + w] = run;
        run += c[i];
    }
}

// distribute edges into window-grouped buffer. Payload packs local dst (9 b)
// and src (17 b, NNODES<2^17) into x; weight bits in y.
__global__ __launch_bounds__(256) void k_scatter(const int* __restrict__ src,
                                                 const int* __restrict__ dst,
                                                 const float* __restrict__ ew,
                                                 const int* __restrict__ block_off,
                                                 int2* __restrict__ esw) {
    __shared__ int myoff[NWIN];
    int t = threadIdx.x, b = blockIdx.x;
    for (int i = t; i < NWIN; i += 256) myoff[i] = block_off[b * NWIN + i];
    __syncthreads();
    int e0 = b * CHUNK;
    for (int e = e0 + t; e < e0 + CHUNK; e += 256) {
        int d = dst[e];
        int w = d >> WSHIFT;
        int pos = atomicAdd(&myoff[w], 1);
        int dl = d - (w << WSHIFT);
        esw[pos] = make_int2((dl << 17) | src[e], __float_as_int(ew[e]));
    }
}

// one block per window: build dense CSR (edges sorted by dst) + raw-weight
// degree sums -> dinv. LDS atomics only; all global traffic coalesced/dense.
__global__ __launch_bounds__(256) void k_fill2(const int* __restrict__ win_base,
                                               const int2* __restrict__ esw,
                                               int2* __restrict__ edges,
                                               int* __restrict__ row_ptr,
                                               int* __restrict__ cnt,
                                               float* __restrict__ dinv) {
    __shared__ int   cnt_l[WIN];
    __shared__ int   sc[WIN];
    __shared__ int   fill_l[WIN];
    __shared__ float degw[WIN];
    int t = threadIdx.x, w = blockIdx.x;
    #pragma unroll
    for (int i = t; i < WIN; i += 256) { cnt_l[i] = 0; fill_l[i] = 0; degw[i] = 0.f; }
    __syncthreads();
    int e0 = win_base[w], e1 = win_base[w + 1];
    for (int e = e0 + t; e < e1; e += 256) {
        int2 v = esw[e];
        int dl = ((unsigned)v.x) >> 17;
        atomicAdd(&cnt_l[dl], 1);
        atomicAdd(&degw[dl], __int_as_float(v.y));
    }
    __syncthreads();
    // inclusive scan of cnt_l (512 entries, 256 threads)
    sc[t] = cnt_l[t]; sc[t + 256] = cnt_l[t + 256];
    __syncthreads();
    for (int off = 1; off < WIN; off <<= 1) {
        int v0 = (t >= off) ? sc[t - off] : 0;
        int v1 = (t + 256 >= off) ? sc[t + 256 - off] : 0;
        __syncthreads();
        sc[t] += v0; sc[t + 256] += v1;
        __syncthreads();
    }
    // exclusive base (global): reuse sc as base_l
    sc[t]       = e0 + sc[t]       - cnt_l[t];
    sc[t + 256] = e0 + sc[t + 256] - cnt_l[t + 256];
    __syncthreads();
    for (int e = e0 + t; e < e1; e += 256) {
        int2 v = esw[e];
        int dl = ((unsigned)v.x) >> 17;
        int pos = sc[dl] + atomicAdd(&fill_l[dl], 1);
        edges[pos] = make_int2(v.x & 0x1FFFF, v.y);
    }
    __syncthreads();
    #pragma unroll
    for (int i = t; i < WIN; i += 256) {
        int node = (w << WSHIFT) + i;
        if (node < NNODES) {
            row_ptr[node] = sc[i];
            cnt[node]     = cnt_l[i];
            dinv[node]    = rsqrtf(degw[i] + 1.0f);
        }
    }
}

// ---------------- GEMM: [200000 x 64] @ [64 x 64] -> fp16, row-scaled -------
// Writes hw'[n] = dinv[n] * (x[n] @ W). TR=true: fp16 input with fused
// GraphNorm affine + ReLU.

template <bool TR>
__global__ __launch_bounds__(256) void k_gemm(const void* __restrict__ Xv,
                                              const float* __restrict__ Wg,
                                              const float* __restrict__ dinv,
                                              __half* __restrict__ Y,
                                              const float* __restrict__ Acoef,
                                              const float* __restrict__ Bcoef) {
    __shared__ __align__(16) float Wl[64 * 64];
    int t = threadIdx.x;
    #pragma unroll
    for (int i = 0; i < 16; i++) Wl[i * 256 + t] = Wg[i * 256 + t];
    __syncthreads();

    int wid  = blockIdx.x * 4 + (t >> 6);
    int lane = t & 63;
    int c = wid & 1;
    int g = wid >> 1;
    int n = g * 64 + lane;
    if (n >= NNODES) return;
    int row = n * 2 + c;
    float dv = dinv[n];

    float4 xr[16];
    if constexpr (!TR) {
        const float* xp = (const float*)Xv + (size_t)row * 64;
        #pragma unroll
        for (int q = 0; q < 16; q++) xr[q] = ((const float4*)xp)[q];
    } else {
        const __half* xp = (const __half*)Xv + (size_t)row * 64;
        #pragma unroll
        for (int q = 0; q < 8; q++) {
            uint4 u = ((const uint4*)xp)[q];
            float2 a = __half22float2(*(const __half2*)&u.x);
            float2 b = __half22float2(*(const __half2*)&u.y);
            float2 cc = __half22float2(*(const __half2*)&u.z);
            float2 d = __half22float2(*(const __half2*)&u.w);
            xr[2 * q]     = make_float4(a.x, a.y, b.x, b.y);
            xr[2 * q + 1] = make_float4(cc.x, cc.y, d.x, d.y);
        }
        const float* A = Acoef + c * 64;
        const float* B = Bcoef + c * 64;
        #pragma unroll
        for (int q = 0; q < 16; q++) {
            float4 a = ((const float4*)A)[q];
            float4 b = ((const float4*)B)[q];
            xr[q].x = fmaxf(a.x * xr[q].x + b.x, 0.0f);
            xr[q].y = fmaxf(a.y * xr[q].y + b.y, 0.0f);
            xr[q].z = fmaxf(a.z * xr[q].z + b.z, 0.0f);
            xr[q].w = fmaxf(a.w * xr[q].w + b.w, 0.0f);
        }
    }

    __half* yp = Y + (size_t)row * 64;
    for (int jg = 0; jg < 16; jg++) {
        float4 acc = make_float4(0.f, 0.f, 0.f, 0.f);
        const float* xs = (const float*)xr;
        #pragma unroll
        for (int k = 0; k < 64; k++) {
            float xv = xs[k];
            float4 w4 = ((const float4*)(Wl + k * 64))[jg];
            acc.x += xv * w4.x; acc.y += xv * w4.y;
            acc.z += xv * w4.z; acc.w += xv * w4.w;
        }
        union { __half2 h2[2]; uint2 u2; } cv;
        cv.h2[0] = __floats2half2_rn(acc.x * dv, acc.y * dv);
        cv.h2[1] = __floats2half2_rn(acc.z * dv, acc.w * dv);
        ((uint2*)yp)[jg] = cv.u2;
    }
}

// ---------------- pull-style GCN aggregation (fp16, dense CSR) -------------
// agg[n] = dinv[n] * (hw'[n] + sum_e ew_e * hw'[src_e]) + bias
// Clamped batch-16 loop: 16 independent gathers in flight, no padding needed.

__global__ __launch_bounds__(256) void k_prop(const __half* __restrict__ hw,
                                              const float* __restrict__ bias,
                                              const float* __restrict__ dinv,
                                              const int* __restrict__ row_ptr,
                                              const int* __restrict__ cnt,
                                              const int2* __restrict__ edges,
                                              __half* __restrict__ agg) {
    int t = threadIdx.x;
    int lane = t & 63;
    int n = __builtin_amdgcn_readfirstlane(blockIdx.x * 4 + (t >> 6));
    if (n >= NNODES) return;

    int f = lane * 2;            // flat half-offset in [0,128), even
    int feat = f & 63;

    float2 bv = *(const float2*)(bias + feat);
    float dv = dinv[n];
    float2 self = __half22float2(*(const __half2*)(hw + (size_t)n * 128 + f));
    float acc0 = self.x;
    float acc1 = self.y;

    int start = row_ptr[n];
    int cn    = cnt[n];
    const unsigned long long* pp = (const unsigned long long*)(edges + start);

    for (int p = 0; p < cn; p += 16) {
        unsigned long long e[16];
        #pragma unroll
        for (int i = 0; i < 16; i++) {
            int q = p + i; q = (q < cn) ? q : (cn - 1);
            e[i] = __builtin_nontemporal_load(pp + q);
        }
        float2 h[16];
        #pragma unroll
        for (int i = 0; i < 16; i++) {
            int s = (int)(e[i] & 0x1FFFFu);
            h[i] = __half22float2(*(const __half2*)(hw + (size_t)s * 128 + f));
        }
        #pragma unroll
        for (int i = 0; i < 16; i++) {
            float w = ((p + i) < cn) ? __int_as_float((int)(e[i] >> 32)) : 0.0f;
            acc0 += w * h[i].x;
            acc1 += w * h[i].y;
        }
    }

    *(__half2*)(agg + (size_t)n * 128 + f) =
        __floats2half2_rn(dv * acc0 + bv.x, dv * acc1 + bv.y);
}

// ---------------- GraphNorm stats (sum, sumsq per column) ----------------

__global__ __launch_bounds__(256) void k_stats(const __half* __restrict__ agg,
                                               float* __restrict__ stats) {
    __shared__ float ls[16][128];
    __shared__ float lq[16][128];
    int t = threadIdx.x;
    int cb = (t & 15) * 8;      // column base
    int rg = t >> 4;            // row group within block (16 rows/iter)
    float s[8], q[8];
    #pragma unroll
    for (int i = 0; i < 8; i++) { s[i] = 0.f; q[i] = 0.f; }
    for (int r = blockIdx.x * 16 + rg; r < NNODES; r += gridDim.x * 16) {
        uint4 u = *(const uint4*)(agg + (size_t)r * 128 + cb);
        const __half2* h2 = (const __half2*)&u;
        #pragma unroll
        for (int i = 0; i < 4; i++) {
            float2 v = __half22float2(h2[i]);
            s[2*i]   += v.x; q[2*i]   += v.x * v.x;
            s[2*i+1] += v.y; q[2*i+1] += v.y * v.y;
        }
    }
    #pragma unroll
    for (int i = 0; i < 8; i++) { ls[rg][cb + i] = s[i]; lq[rg][cb + i] = q[i]; }
    __syncthreads();
    if (t < 128) {
        float a = 0.f, b = 0.f;
        #pragma unroll
        for (int g = 0; g < 16; g++) { a += ls[g][t]; b += lq[g][t]; }
        atomicAdd(&stats[t], a);
        atomicAdd(&stats[128 + t], b);
    }
}

__global__ void k_coef(float* stats, const float* __restrict__ gn_w,
                       const float* __restrict__ gn_b, const float* __restrict__ gn_ms) {
    int col = threadIdx.x;  // 128
    float inv_n = 1.0f / (float)NNODES;
    float mean = stats[col] * inv_n;
    float eh2  = stats[128 + col] * inv_n;
    int f = col & 63;
    float ms = gn_ms[f];
    float var = eh2 - 2.0f * ms * mean * mean + ms * ms * mean * mean;
    float A = gn_w[f] * rsqrtf(var + 1e-5f);
    stats[256 + col] = A;
    stats[384 + col] = gn_b[f] - A * ms * mean;
}

// ---------------- fused subgraph pooling + MLP head ----------------

__global__ __launch_bounds__(128) void k_head(const __half* __restrict__ agg,
                                              const int* __restrict__ subg,
                                              const float* __restrict__ mW1,
                                              const float* __restrict__ mb1,
                                              const float* __restrict__ mW2,
                                              const float* __restrict__ mb2,
                                              float* __restrict__ out) {
    __shared__ float pl[128];
    __shared__ float red[128];
    int s = blockIdx.x, t = threadIdx.x;
    int j = t & 63, half = t >> 6;
    const int* idx = subg + s * 64;
    float acc = 0.f;
    for (int m = half * 32; m < half * 32 + 32; m++) {
        int n = idx[m];
        acc += 0.5f * (__half2float(agg[(size_t)n * 128 + j]) +
                       __half2float(agg[(size_t)n * 128 + 64 + j]));
    }
    pl[half * 64 + j] = acc;
    __syncthreads();
    if (t < 64) pl[t] += pl[64 + t];
    __syncthreads();
    float h = mb1[t];
    #pragma unroll
    for (int k = 0; k < 64; k++) h += pl[k] * mW1[k * 128 + t];
    h = fmaxf(h, 0.0f);
    red[t] = h * mW2[t];
    __syncthreads();
    for (int off = 64; off > 0; off >>= 1) {
        if (t < off) red[t] += red[t + off];
        __syncthreads();
    }
    if (t == 0) out[s] = red[0] + mb2[0];
}

// ---------------- launcher ----------------

extern "C" void kernel_launch(void* const* d_in, const int* in_sizes, int n_in,
                              void* d_out, int out_size, void* d_ws, size_t ws_size,
                              hipStream_t stream) {
    const float* x     = (const float*)d_in[0];
    const int*   ei    = (const int*)d_in[1];
    const float* ew    = (const float*)d_in[2];
    const int*   subg  = (const int*)d_in[3];
    const float* W1    = (const float*)d_in[4];
    const float* b1    = (const float*)d_in[5];
    const float* gn_w  = (const float*)d_in[6];
    const float* gn_b  = (const float*)d_in[7];
    const float* gn_ms = (const float*)d_in[8];
    const float* W2    = (const float*)d_in[9];
    const float* b2    = (const float*)d_in[10];
    const float* mW1   = (const float*)d_in[11];
    const float* mb1   = (const float*)d_in[12];
    const float* mW2   = (const float*)d_in[13];
    const float* mb2   = (const float*)d_in[14];
    float* out = (float*)d_out;

    char* w = (char*)d_ws;
    size_t off = 0;
    auto alloc = [&](size_t bytes) {
        void* p = w + off;
        off = (off + bytes + 255) & ~(size_t)255;
        return p;
    };
    float*  dinv      = (float*) alloc((size_t)NNODES * 4);
    int*    cnt       = (int*)   alloc((size_t)NNODES * 4);
    int*    row_ptr   = (int*)   alloc((size_t)NNODES * 4);
    int2*   edges     = (int2*)  alloc((size_t)NEDGES * 8);        // 12.8 MB
    int2*   esw       = (int2*)  alloc((size_t)NEDGES * 8);        // 12.8 MB
    __half* hw        = (__half*)alloc((size_t)NNODES * 128 * 2);  // 25.6 MB
    __half* agg       = (__half*)alloc((size_t)NNODES * 128 * 2);  // 25.6 MB
    float*  stats     = (float*) alloc(512 * 4);
    int*    block_counts = (int*)alloc((size_t)NBLK * NWIN * 4);   // 200 KB
    int*    block_off    = (int*)alloc((size_t)NBLK * NWIN * 4);   // 200 KB
    int*    win_total    = (int*)alloc(NWIN * 4);
    int*    win_base     = (int*)alloc((NWIN + 1) * 4);

    const int* src = ei;
    const int* dst = ei + NEDGES;

    // edge binning (counting sort by 512-node dst window) -> dense CSR + dinv
    k_hist   <<<NBLK, 256, 0, stream>>>(dst, block_counts);
    k_winsum <<<NWIN, 256, 0, stream>>>(block_counts, win_total);
    k_scan   <<<1, 256, 0, stream>>>(win_total, win_base, stats);
    k_scan2  <<<NWIN, 64, 0, stream>>>(block_counts, win_base, block_off);
    k_scatter<<<NBLK, 256, 0, stream>>>(src, dst, ew, block_off, esw);
    k_fill2  <<<NWIN, 256, 0, stream>>>(win_base, esw, edges, row_ptr, cnt, dinv);

    // layer 1
    k_gemm<false><<<782, 256, 0, stream>>>(x, W1, dinv, hw, nullptr, nullptr);
    k_prop<<<25000, 256, 0, stream>>>(hw, b1, dinv, row_ptr, cnt, edges, agg);

    // GraphNorm coefficients
    k_stats<<<512, 256, 0, stream>>>(agg, stats);
    k_coef<<<1, 128, 0, stream>>>(stats, gn_w, gn_b, gn_ms);

    // layer 2 (GraphNorm+ReLU fused into GEMM2 input)
    k_gemm<true><<<782, 256, 0, stream>>>(agg, W2, dinv, hw, stats + 256, stats + 384);
    k_prop<<<25000, 256, 0, stream>>>(hw, b2, dinv, row_ptr, cnt, edges, agg);

    // fused pooling + MLP head
    k_head<<<NSUB, 128, 0, stream>>>(agg, subg, mW1, mb1, mW2, mb2, out);
}

// Round 8
// 382.870 us; speedup vs baseline: 1.6126x; 1.0879x over previous
//
#include <hip/hip_runtime.h>
#include <hip/hip_fp16.h>

#define NNODES 100000
#define NEDGES 1600000
#define NSUB   1000
#define MSUB   64
#define MHID   128

#define WSHIFT 9                         // 512-node dst windows
#define WIN    512
#define NWIN   ((NNODES + 511) >> 9)     // 196
#define NBLK   256                       // blocks for hist/scatter
#define CHUNK  (NEDGES / NBLK)           // 6250 exact

typedef _Float16 f16x8 __attribute__((ext_vector_type(8)));
typedef float    f32x4 __attribute__((ext_vector_type(4)));

// ---------------- edge binning: counting sort by dst window ----------------

__global__ __launch_bounds__(256) void k_hist(const int* __restrict__ dst,
                                              int* __restrict__ block_counts) {
    __shared__ int hist[NWIN];
    int t = threadIdx.x, b = blockIdx.x;
    for (int i = t; i < NWIN; i += 256) hist[i] = 0;
    __syncthreads();
    int e0 = b * CHUNK;
    for (int e = e0 + t; e < e0 + CHUNK; e += 256)
        atomicAdd(&hist[dst[e] >> WSHIFT], 1);
    __syncthreads();
    for (int i = t; i < NWIN; i += 256) block_counts[b * NWIN + i] = hist[i];
}

__global__ __launch_bounds__(256) void k_winsum(const int* __restrict__ block_counts,
                                                int* __restrict__ win_total) {
    __shared__ int red[256];
    int t = threadIdx.x, w = blockIdx.x;
    red[t] = block_counts[t * NWIN + w];
    __syncthreads();
    for (int off = 128; off > 0; off >>= 1) {
        if (t < off) red[t] += red[t + off];
        __syncthreads();
    }
    if (t == 0) win_total[w] = red[0];
}

// tiny: exclusive scan of 196 window totals; zero stats; write edge guard
__global__ __launch_bounds__(256) void k_scan(const int* __restrict__ win_total,
                                              int* __restrict__ win_base,
                                              float* __restrict__ stats,
                                              int2* __restrict__ edges) {
    __shared__ int arr[256];
    int t = threadIdx.x;
    int own = (t < NWIN) ? win_total[t] : 0;
    arr[t] = own;
    __syncthreads();
    for (int off = 1; off < 256; off <<= 1) {
        int v = (t >= off) ? arr[t - off] : 0;
        __syncthreads();
        arr[t] += v;
        __syncthreads();
    }
    if (t < NWIN) win_base[t] = arr[t] - own;
    if (t == NWIN - 1) win_base[NWIN] = arr[t];
    stats[t] = 0.0f; stats[t + 256] = 0.0f;
    if (t < 16) edges[NEDGES + t] = make_int2(0, 0);   // guard for k_prop over-read
}

__global__ __launch_bounds__(64) void k_scan2(const int* __restrict__ block_counts,
                                              const int* __restrict__ win_base,
                                              int* __restrict__ block_off) {
    int w = blockIdx.x, lane = threadIdx.x;
    int c[4];
    int lsum = 0;
    #pragma unroll
    for (int i = 0; i < 4; i++) {
        c[i] = block_counts[(lane * 4 + i) * NWIN + w];
        lsum += c[i];
    }
    int incl = lsum;
    #pragma unroll
    for (int off = 1; off < 64; off <<= 1) {
        int u = __shfl_up(incl, off, 64);
        if (lane >= off) incl += u;
    }
    int run = win_base[w] + incl - lsum;
    #pragma unroll
    for (int i = 0; i < 4; i++) {
        block_off[(lane * 4 + i) * NWIN + w] = run;
        run += c[i];
    }
}

__global__ __launch_bounds__(256) void k_scatter(const int* __restrict__ src,
                                                 const int* __restrict__ dst,
                                                 const float* __restrict__ ew,
                                                 const int* __restrict__ block_off,
                                                 int2* __restrict__ esw) {
    __shared__ int myoff[NWIN];
    int t = threadIdx.x, b = blockIdx.x;
    for (int i = t; i < NWIN; i += 256) myoff[i] = block_off[b * NWIN + i];
    __syncthreads();
    int e0 = b * CHUNK;
    for (int e = e0 + t; e < e0 + CHUNK; e += 256) {
        int d = dst[e];
        int w = d >> WSHIFT;
        int pos = atomicAdd(&myoff[w], 1);
        int dl = d - (w << WSHIFT);
        esw[pos] = make_int2((dl << 17) | src[e], __float_as_int(ew[e]));
    }
}

// one block per window: build dense CSR (edges sorted by dst) + raw-weight
// degree sums -> dinv.
__global__ __launch_bounds__(256) void k_fill2(const int* __restrict__ win_base,
                                               const int2* __restrict__ esw,
                                               int2* __restrict__ edges,
                                               int* __restrict__ row_ptr,
                                               int* __restrict__ cnt,
                                               float* __restrict__ dinv) {
    __shared__ int   cnt_l[WIN];
    __shared__ int   sc[WIN];
    __shared__ int   fill_l[WIN];
    __shared__ float degw[WIN];
    int t = threadIdx.x, w = blockIdx.x;
    #pragma unroll
    for (int i = t; i < WIN; i += 256) { cnt_l[i] = 0; fill_l[i] = 0; degw[i] = 0.f; }
    __syncthreads();
    int e0 = win_base[w], e1 = win_base[w + 1];
    for (int e = e0 + t; e < e1; e += 256) {
        int2 v = esw[e];
        int dl = ((unsigned)v.x) >> 17;
        atomicAdd(&cnt_l[dl], 1);
        atomicAdd(&degw[dl], __int_as_float(v.y));
    }
    __syncthreads();
    sc[t] = cnt_l[t]; sc[t + 256] = cnt_l[t + 256];
    __syncthreads();
    for (int off = 1; off < WIN; off <<= 1) {
        int v0 = (t >= off) ? sc[t - off] : 0;
        int v1 = (t + 256 >= off) ? sc[t + 256 - off] : 0;
        __syncthreads();
        sc[t] += v0; sc[t + 256] += v1;
        __syncthreads();
    }
    sc[t]       = e0 + sc[t]       - cnt_l[t];
    sc[t + 256] = e0 + sc[t + 256] - cnt_l[t + 256];
    __syncthreads();
    for (int e = e0 + t; e < e1; e += 256) {
        int2 v = esw[e];
        int dl = ((unsigned)v.x) >> 17;
        int pos = sc[dl] + atomicAdd(&fill_l[dl], 1);
        edges[pos] = make_int2(v.x & 0x1FFFF, v.y);
    }
    __syncthreads();
    #pragma unroll
    for (int i = t; i < WIN; i += 256) {
        int node = (w << WSHIFT) + i;
        if (node < NNODES) {
            row_ptr[node] = sc[i];
            cnt[node]     = cnt_l[i];
            dinv[node]    = rsqrtf(degw[i] + 1.0f);
        }
    }
}

// ---------------- MFMA GEMM: [200000 x 64] @ [64 x 64] -> fp16, row-scaled --
// Wave = one 16-row x 64-col tile, K=64: 8 x mfma_f32_16x16x32_f16.
// B (W columns) held in registers, loaded once per wave. A loaded from global
// (fp32->fp16 for TR=false; fp16 + fused GraphNorm affine + ReLU for TR=true).
// Epilogue scales rows by dinv, bounces through LDS for coalesced fp16 stores.
// 200000 rows = 12500 tiles exactly -> no bounds checks.

template <bool TR>
__global__ __launch_bounds__(256) void k_gemm(const void* __restrict__ Xv,
                                              const float* __restrict__ Wg,
                                              const float* __restrict__ dinv,
                                              _Float16* __restrict__ Y,
                                              const float* __restrict__ Acoef,
                                              const float* __restrict__ Bcoef) {
    __shared__ __align__(16) _Float16 ob[4][16 * 72];   // per-wave 16x64 (+pad 8)
    int t = threadIdx.x;
    int wave = t >> 6, lane = t & 63;
    int m = lane & 15, q = lane >> 4;

    // B fragments: B[k = kb*32 + q*8 + j][n = nt*16 + m]
    f16x8 bf[2][4];
    #pragma unroll
    for (int kb = 0; kb < 2; kb++)
        #pragma unroll
        for (int nt = 0; nt < 4; nt++)
            #pragma unroll
            for (int j = 0; j < 8; j++)
                bf[kb][nt][j] = (_Float16)Wg[(kb * 32 + q * 8 + j) * 64 + nt * 16 + m];

    float ca[16], cb[16];
    if constexpr (TR) {
        int c = m & 1;     // row = n*2+c -> channel = row & 1 = m & 1
        #pragma unroll
        for (int kb = 0; kb < 2; kb++)
            #pragma unroll
            for (int j = 0; j < 8; j++) {
                int k = kb * 32 + q * 8 + j;
                ca[kb * 8 + j] = Acoef[c * 64 + k];
                cb[kb * 8 + j] = Bcoef[c * 64 + k];
            }
    }

    int tile = blockIdx.x * 4 + wave;
    int row0 = tile * 16;

    f16x8 af[2];
    if constexpr (!TR) {
        const float* xp = (const float*)Xv + (size_t)(row0 + m) * 64;
        #pragma unroll
        for (int kb = 0; kb < 2; kb++) {
            float4 u0 = *(const float4*)(xp + kb * 32 + q * 8);
            float4 u1 = *(const float4*)(xp + kb * 32 + q * 8 + 4);
            af[kb][0] = (_Float16)u0.x; af[kb][1] = (_Float16)u0.y;
            af[kb][2] = (_Float16)u0.z; af[kb][3] = (_Float16)u0.w;
            af[kb][4] = (_Float16)u1.x; af[kb][5] = (_Float16)u1.y;
            af[kb][6] = (_Float16)u1.z; af[kb][7] = (_Float16)u1.w;
        }
    } else {
        const _Float16* xp = (const _Float16*)Xv + (size_t)(row0 + m) * 64;
        #pragma unroll
        for (int kb = 0; kb < 2; kb++) {
            f16x8 v = *(const f16x8*)(xp + kb * 32 + q * 8);
            #pragma unroll
            for (int j = 0; j < 8; j++) {
                float f = (float)v[j];
                f = fmaxf(ca[kb * 8 + j] * f + cb[kb * 8 + j], 0.0f);
                af[kb][j] = (_Float16)f;
            }
        }
    }

    f32x4 acc[4];
    #pragma unroll
    for (int nt = 0; nt < 4; nt++) {
        acc[nt] = (f32x4){0.f, 0.f, 0.f, 0.f};
        acc[nt] = __builtin_amdgcn_mfma_f32_16x16x32_f16(af[0], bf[0][nt], acc[nt], 0, 0, 0);
        acc[nt] = __builtin_amdgcn_mfma_f32_16x16x32_f16(af[1], bf[1][nt], acc[nt], 0, 0, 0);
    }

    float dv[4];
    #pragma unroll
    for (int i = 0; i < 4; i++) dv[i] = dinv[(row0 + q * 4 + i) >> 1];

    _Float16* obw = ob[wave];
    #pragma unroll
    for (int nt = 0; nt < 4; nt++)
        #pragma unroll
        for (int i = 0; i < 4; i++)
            obw[(q * 4 + i) * 72 + nt * 16 + m] = (_Float16)(acc[nt][i] * dv[i]);
    __syncthreads();

    _Float16* yp = Y + (size_t)row0 * 64;
    #pragma unroll
    for (int s = 0; s < 2; s++) {
        int c8 = s * 64 + lane;          // 16B-chunk index, 128 per tile
        int r = c8 >> 3, cg = c8 & 7;
        uint4 v = *(const uint4*)(obw + r * 72 + cg * 8);
        *(uint4*)(yp + (size_t)r * 64 + cg * 8) = v;
    }
}

// ---------------- pull-style GCN aggregation (fp16, dense CSR) -------------
// agg[n] = dinv[n] * (hw'[n] + sum_e ew_e * hw'[src_e]) + bias
// Unclamped batch-16 reads (guard entries keep them in-bounds); only the
// weight is masked for the tail.

__global__ __launch_bounds__(256) void k_prop(const __half* __restrict__ hw,
                                              const float* __restrict__ bias,
                                              const float* __restrict__ dinv,
                                              const int* __restrict__ row_ptr,
                                              const int* __restrict__ cnt,
                                              const int2* __restrict__ edges,
                                              __half* __restrict__ agg) {
    int t = threadIdx.x;
    int lane = t & 63;
    int n = __builtin_amdgcn_readfirstlane(blockIdx.x * 4 + (t >> 6));
    if (n >= NNODES) return;

    int f = lane * 2;            // flat half-offset in [0,128), even
    int feat = f & 63;

    float2 bv = *(const float2*)(bias + feat);
    float dv = dinv[n];
    float2 self = __half22float2(*(const __half2*)(hw + (size_t)n * 128 + f));
    float acc0 = self.x;
    float acc1 = self.y;

    int start = row_ptr[n];
    int cn    = cnt[n];
    const unsigned long long* pp = (const unsigned long long*)(edges + start);

    for (int p = 0; p < cn; p += 16) {
        unsigned long long e[16];
        #pragma unroll
        for (int i = 0; i < 16; i++) e[i] = __builtin_nontemporal_load(pp + p + i);
        float2 h[16];
        #pragma unroll
        for (int i = 0; i < 16; i++) {
            int s = (int)(e[i] & 0x1FFFFu);
            h[i] = __half22float2(*(const __half2*)(hw + (size_t)s * 128 + f));
        }
        #pragma unroll
        for (int i = 0; i < 16; i++) {
            float w = ((p + i) < cn) ? __int_as_float((int)(e[i] >> 32)) : 0.0f;
            acc0 += w * h[i].x;
            acc1 += w * h[i].y;
        }
    }

    *(__half2*)(agg + (size_t)n * 128 + f) =
        __floats2half2_rn(dv * acc0 + bv.x, dv * acc1 + bv.y);
}

// ---------------- GraphNorm stats (sum, sumsq per column) ----------------

__global__ __launch_bounds__(256) void k_stats(const __half* __restrict__ agg,
                                               float* __restrict__ stats) {
    __shared__ float ls[16][128];
    __shared__ float lq[16][128];
    int t = threadIdx.x;
    int cb = (t & 15) * 8;
    int rg = t >> 4;
    float s[8], q[8];
    #pragma unroll
    for (int i = 0; i < 8; i++) { s[i] = 0.f; q[i] = 0.f; }
    for (int r = blockIdx.x * 16 + rg; r < NNODES; r += gridDim.x * 16) {
        uint4 u = *(const uint4*)(agg + (size_t)r * 128 + cb);
        const __half2* h2 = (const __half2*)&u;
        #pragma unroll
        for (int i = 0; i < 4; i++) {
            float2 v = __half22float2(h2[i]);
            s[2*i]   += v.x; q[2*i]   += v.x * v.x;
            s[2*i+1] += v.y; q[2*i+1] += v.y * v.y;
        }
    }
    #pragma unroll
    for (int i = 0; i < 8; i++) { ls[rg][cb + i] = s[i]; lq[rg][cb + i] = q[i]; }
    __syncthreads();
    if (t < 128) {
        float a = 0.f, b = 0.f;
        #pragma unroll
        for (int g = 0; g < 16; g++) { a += ls[g][t]; b += lq[g][t]; }
        atomicAdd(&stats[t], a);
        atomicAdd(&stats[128 + t], b);
    }
}

__global__ void k_coef(float* stats, const float* __restrict__ gn_w,
                       const float* __restrict__ gn_b, const float* __restrict__ gn_ms) {
    int col = threadIdx.x;  // 128
    float inv_n = 1.0f / (float)NNODES;
    float mean = stats[col] * inv_n;
    float eh2  = stats[128 + col] * inv_n;
    int f = col & 63;
    float ms = gn_ms[f];
    float var = eh2 - 2.0f * ms * mean * mean + ms * ms * mean * mean;
    float A = gn_w[f] * rsqrtf(var + 1e-5f);
    stats[256 + col] = A;
    stats[384 + col] = gn_b[f] - A * ms * mean;
}

// ---------------- fused subgraph pooling + MLP head ----------------

__global__ __launch_bounds__(128) void k_head(const __half* __restrict__ agg,
                                              const int* __restrict__ subg,
                                              const float* __restrict__ mW1,
                                              const float* __restrict__ mb1,
                                              const float* __restrict__ mW2,
                                              const float* __restrict__ mb2,
                                              float* __restrict__ out) {
    __shared__ float pl[128];
    __shared__ float red[128];
    int s = blockIdx.x, t = threadIdx.x;
    int j = t & 63, half = t >> 6;
    const int* idx = subg + s * 64;
    float acc = 0.f;
    for (int m = half * 32; m < half * 32 + 32; m++) {
        int n = idx[m];
        acc += 0.5f * (__half2float(agg[(size_t)n * 128 + j]) +
                       __half2float(agg[(size_t)n * 128 + 64 + j]));
    }
    pl[half * 64 + j] = acc;
    __syncthreads();
    if (t < 64) pl[t] += pl[64 + t];
    __syncthreads();
    float h = mb1[t];
    #pragma unroll
    for (int k = 0; k < 64; k++) h += pl[k] * mW1[k * 128 + t];
    h = fmaxf(h, 0.0f);
    red[t] = h * mW2[t];
    __syncthreads();
    for (int off = 64; off > 0; off >>= 1) {
        if (t < off) red[t] += red[t + off];
        __syncthreads();
    }
    if (t == 0) out[s] = red[0] + mb2[0];
}

// ---------------- launcher ----------------

extern "C" void kernel_launch(void* const* d_in, const int* in_sizes, int n_in,
                              void* d_out, int out_size, void* d_ws, size_t ws_size,
                              hipStream_t stream) {
    const float* x     = (const float*)d_in[0];
    const int*   ei    = (const int*)d_in[1];
    const float* ew    = (const float*)d_in[2];
    const int*   subg  = (const int*)d_in[3];
    const float* W1    = (const float*)d_in[4];
    const float* b1    = (const float*)d_in[5];
    const float* gn_w  = (const float*)d_in[6];
    const float* gn_b  = (const float*)d_in[7];
    const float* gn_ms = (const float*)d_in[8];
    const float* W2    = (const float*)d_in[9];
    const float* b2    = (const float*)d_in[10];
    const float* mW1   = (const float*)d_in[11];
    const float* mb1   = (const float*)d_in[12];
    const float* mW2   = (const float*)d_in[13];
    const float* mb2   = (const float*)d_in[14];
    float* out = (float*)d_out;

    char* w = (char*)d_ws;
    size_t off = 0;
    auto alloc = [&](size_t bytes) {
        void* p = w + off;
        off = (off + bytes + 255) & ~(size_t)255;
        return p;
    };
    float*  dinv      = (float*) alloc((size_t)NNODES * 4);
    int*    cnt       = (int*)   alloc((size_t)NNODES * 4);
    int*    row_ptr   = (int*)   alloc((size_t)NNODES * 4);
    int2*   edges     = (int2*)  alloc(((size_t)NEDGES + 16) * 8);  // +guard
    int2*   esw       = (int2*)  alloc((size_t)NEDGES * 8);
    __half* hw        = (__half*)alloc((size_t)NNODES * 128 * 2);
    __half* agg       = (__half*)alloc((size_t)NNODES * 128 * 2);
    float*  stats     = (float*) alloc(512 * 4);
    int*    block_counts = (int*)alloc((size_t)NBLK * NWIN * 4);
    int*    block_off    = (int*)alloc((size_t)NBLK * NWIN * 4);
    int*    win_total    = (int*)alloc(NWIN * 4);
    int*    win_base     = (int*)alloc((NWIN + 1) * 4);

    const int* src = ei;
    const int* dst = ei + NEDGES;

    // edge binning (counting sort by 512-node dst window) -> dense CSR + dinv
    k_hist   <<<NBLK, 256, 0, stream>>>(dst, block_counts);
    k_winsum <<<NWIN, 256, 0, stream>>>(block_counts, win_total);
    k_scan   <<<1, 256, 0, stream>>>(win_total, win_base, stats, edges);
    k_scan2  <<<NWIN, 64, 0, stream>>>(block_counts, win_base, block_off);
    k_scatter<<<NBLK, 256, 0, stream>>>(src, dst, ew, block_off, esw);
    k_fill2  <<<NWIN, 256, 0, stream>>>(win_base, esw, edges, row_ptr, cnt, dinv);

    // layer 1
    k_gemm<false><<<3125, 256, 0, stream>>>(x, W1, dinv, (_Float16*)hw, nullptr, nullptr);
    k_prop<<<25000, 256, 0, stream>>>(hw, b1, dinv, row_ptr, cnt, edges, agg);

    // GraphNorm coefficients
    k_stats<<<512, 256, 0, stream>>>(agg, stats);
    k_coef<<<1, 128, 0, stream>>>(stats, gn_w, gn_b, gn_ms);

    // layer 2 (GraphNorm+ReLU fused into GEMM2 input)
    k_gemm<true><<<3125, 256, 0, stream>>>(agg, W2, dinv, (_Float16*)hw, stats + 256, stats + 384);
    k_prop<<<25000, 256, 0, stream>>>(hw, b2, dinv, row_ptr, cnt, edges, agg);

    // fused pooling + MLP head
    k_head<<<NSUB, 128, 0, stream>>>(agg, subg, mW1, mb1, mW2, mb2, out);
}

// Round 9
// 354.584 us; speedup vs baseline: 1.7413x; 1.0798x over previous
//
#include <hip/hip_runtime.h>
#include <hip/hip_fp16.h>

#define NNODES 100000
#define NEDGES 1600000
#define NSUB   1000
#define MSUB   64
#define MHID   128

#define WSHIFT 9                         // 512-node dst windows
#define WIN    512
#define NWIN   ((NNODES + 511) >> 9)     // 196
#define NBLK   256                       // blocks for hist/scatter
#define CHUNK  (NEDGES / NBLK)           // 6250 exact

typedef _Float16 f16x8 __attribute__((ext_vector_type(8)));
typedef float    f32x4 __attribute__((ext_vector_type(4)));

// ---------------- edge binning: counting sort by dst window ----------------

__global__ __launch_bounds__(256) void k_hist(const int* __restrict__ dst,
                                              int* __restrict__ block_counts,
                                              int* __restrict__ cursor) {
    __shared__ int hist[NWIN];
    int t = threadIdx.x, b = blockIdx.x;
    if (b == 0 && t == 0) *cursor = 0;
    for (int i = t; i < NWIN; i += 256) hist[i] = 0;
    __syncthreads();
    int e0 = b * CHUNK;
    for (int e = e0 + t; e < e0 + CHUNK; e += 256)
        atomicAdd(&hist[dst[e] >> WSHIFT], 1);
    __syncthreads();
    for (int i = t; i < NWIN; i += 256) block_counts[b * NWIN + i] = hist[i];
}

// one block per window: total (reduce) -> base (atomic cursor; window order in
// the CSR is arbitrary but contiguous) -> per-block offsets (scan). Also zeroes
// stats and writes the prop guard entries (block 0).
__global__ __launch_bounds__(256) void k_off(const int* __restrict__ block_counts,
                                             int* __restrict__ cursor,
                                             int* __restrict__ win_base,
                                             int* __restrict__ win_lim,
                                             int* __restrict__ block_off,
                                             float* __restrict__ stats,
                                             unsigned* __restrict__ edges) {
    __shared__ int arr[256];
    __shared__ int red[256];
    __shared__ int base_s;
    int t = threadIdx.x, w = blockIdx.x;
    int own = block_counts[t * NWIN + w];
    arr[t] = own; red[t] = own;
    __syncthreads();
    for (int off = 128; off > 0; off >>= 1) {
        if (t < off) red[t] += red[t + off];
        __syncthreads();
    }
    if (t == 0) base_s = atomicAdd(cursor, red[0]);
    for (int off = 1; off < 256; off <<= 1) {
        int v = (t >= off) ? arr[t - off] : 0;
        __syncthreads();
        arr[t] += v;
        __syncthreads();
    }
    int base = base_s;
    block_off[t * NWIN + w] = base + arr[t] - own;
    if (t == 0) { win_base[w] = base; win_lim[w] = base + red[0]; }
    if (w == 0) {
        stats[t] = 0.0f; stats[t + 256] = 0.0f;
        if (t < 16) edges[NEDGES + t] = 0u;
    }
}

__global__ __launch_bounds__(256) void k_scatter(const int* __restrict__ src,
                                                 const int* __restrict__ dst,
                                                 const float* __restrict__ ew,
                                                 const int* __restrict__ block_off,
                                                 int2* __restrict__ esw) {
    __shared__ int myoff[NWIN];
    int t = threadIdx.x, b = blockIdx.x;
    for (int i = t; i < NWIN; i += 256) myoff[i] = block_off[b * NWIN + i];
    __syncthreads();
    int e0 = b * CHUNK;
    for (int e = e0 + t; e < e0 + CHUNK; e += 256) {
        int d = dst[e];
        int w = d >> WSHIFT;
        int pos = atomicAdd(&myoff[w], 1);
        int dl = d - (w << WSHIFT);
        esw[pos] = make_int2((dl << 17) | src[e], __float_as_int(ew[e]));
    }
}

// one block per window: dense CSR (4 B packed entries: wq15<<17 | src17) +
// raw-weight degree sums -> dinv.
__global__ __launch_bounds__(256) void k_fill2(const int* __restrict__ win_base,
                                               const int* __restrict__ win_lim,
                                               const int2* __restrict__ esw,
                                               unsigned* __restrict__ edges,
                                               int* __restrict__ row_ptr,
                                               int* __restrict__ cnt,
                                               float* __restrict__ dinv) {
    __shared__ int   cnt_l[WIN];
    __shared__ int   sc[WIN];
    __shared__ int   fill_l[WIN];
    __shared__ float degw[WIN];
    int t = threadIdx.x, w = blockIdx.x;
    #pragma unroll
    for (int i = t; i < WIN; i += 256) { cnt_l[i] = 0; fill_l[i] = 0; degw[i] = 0.f; }
    __syncthreads();
    int e0 = win_base[w], e1 = win_lim[w];
    for (int e = e0 + t; e < e1; e += 256) {
        int2 v = esw[e];
        int dl = ((unsigned)v.x) >> 17;
        atomicAdd(&cnt_l[dl], 1);
        atomicAdd(&degw[dl], __int_as_float(v.y));
    }
    __syncthreads();
    sc[t] = cnt_l[t]; sc[t + 256] = cnt_l[t + 256];
    __syncthreads();
    for (int off = 1; off < WIN; off <<= 1) {
        int v0 = (t >= off) ? sc[t - off] : 0;
        int v1 = (t + 256 >= off) ? sc[t + 256 - off] : 0;
        __syncthreads();
        sc[t] += v0; sc[t + 256] += v1;
        __syncthreads();
    }
    sc[t]       = e0 + sc[t]       - cnt_l[t];
    sc[t + 256] = e0 + sc[t + 256] - cnt_l[t + 256];
    __syncthreads();
    for (int e = e0 + t; e < e1; e += 256) {
        int2 v = esw[e];
        int dl = ((unsigned)v.x) >> 17;
        int pos = sc[dl] + atomicAdd(&fill_l[dl], 1);
        int wq = __float2int_rn(__int_as_float(v.y) * 32767.0f);
        edges[pos] = ((unsigned)wq << 17) | ((unsigned)v.x & 0x1FFFFu);
    }
    __syncthreads();
    #pragma unroll
    for (int i = t; i < WIN; i += 256) {
        int node = (w << WSHIFT) + i;
        if (node < NNODES) {
            row_ptr[node] = sc[i];
            cnt[node]     = cnt_l[i];
            dinv[node]    = rsqrtf(degw[i] + 1.0f);
        }
    }
}

// ---------------- MFMA GEMM: [200000 x 64] @ [64 x 64] -> fp16, row-scaled --
// Wave = one 16x64 tile, K=64: 8 x mfma_f32_16x16x32_f16. TR=true computes
// GraphNorm coefs per-thread from stats (k_coef folded in).

template <bool TR>
__global__ __launch_bounds__(256) void k_gemm(const void* __restrict__ Xv,
                                              const float* __restrict__ Wg,
                                              const float* __restrict__ dinv,
                                              _Float16* __restrict__ Y,
                                              const float* __restrict__ stats,
                                              const float* __restrict__ gn_w,
                                              const float* __restrict__ gn_b,
                                              const float* __restrict__ gn_ms) {
    __shared__ __align__(16) _Float16 ob[4][16 * 72];   // per-wave 16x64 (+pad 8)
    int t = threadIdx.x;
    int wave = t >> 6, lane = t & 63;
    int m = lane & 15, q = lane >> 4;

    // B fragments: B[k = kb*32 + q*8 + j][n = nt*16 + m]
    f16x8 bf[2][4];
    #pragma unroll
    for (int kb = 0; kb < 2; kb++)
        #pragma unroll
        for (int nt = 0; nt < 4; nt++)
            #pragma unroll
            for (int j = 0; j < 8; j++)
                bf[kb][nt][j] = (_Float16)Wg[(kb * 32 + q * 8 + j) * 64 + nt * 16 + m];

    float ca[16], cb[16];
    if constexpr (TR) {
        int c = m & 1;     // row = n*2+c -> channel = m & 1
        const float inv_n = 1.0f / (float)NNODES;
        #pragma unroll
        for (int kb = 0; kb < 2; kb++)
            #pragma unroll
            for (int j = 0; j < 8; j++) {
                int k = kb * 32 + q * 8 + j;
                int col = c * 64 + k;
                float mean = stats[col] * inv_n;
                float eh2  = stats[128 + col] * inv_n;
                float ms   = gn_ms[k];
                float mm   = ms * mean;
                float var  = eh2 - 2.0f * mm * mean + mm * mm;
                float A = gn_w[k] * rsqrtf(var + 1e-5f);
                ca[kb * 8 + j] = A;
                cb[kb * 8 + j] = gn_b[k] - A * mm;
            }
    }

    int tile = blockIdx.x * 4 + wave;
    int row0 = tile * 16;

    f16x8 af[2];
    if constexpr (!TR) {
        const float* xp = (const float*)Xv + (size_t)(row0 + m) * 64;
        #pragma unroll
        for (int kb = 0; kb < 2; kb++) {
            float4 u0 = *(const float4*)(xp + kb * 32 + q * 8);
            float4 u1 = *(const float4*)(xp + kb * 32 + q * 8 + 4);
            af[kb][0] = (_Float16)u0.x; af[kb][1] = (_Float16)u0.y;
            af[kb][2] = (_Float16)u0.z; af[kb][3] = (_Float16)u0.w;
            af[kb][4] = (_Float16)u1.x; af[kb][5] = (_Float16)u1.y;
            af[kb][6] = (_Float16)u1.z; af[kb][7] = (_Float16)u1.w;
        }
    } else {
        const _Float16* xp = (const _Float16*)Xv + (size_t)(row0 + m) * 64;
        #pragma unroll
        for (int kb = 0; kb < 2; kb++) {
            f16x8 v = *(const f16x8*)(xp + kb * 32 + q * 8);
            #pragma unroll
            for (int j = 0; j < 8; j++) {
                float f = (float)v[j];
                f = fmaxf(ca[kb * 8 + j] * f + cb[kb * 8 + j], 0.0f);
                af[kb][j] = (_Float16)f;
            }
        }
    }

    f32x4 acc[4];
    #pragma unroll
    for (int nt = 0; nt < 4; nt++) {
        acc[nt] = (f32x4){0.f, 0.f, 0.f, 0.f};
        acc[nt] = __builtin_amdgcn_mfma_f32_16x16x32_f16(af[0], bf[0][nt], acc[nt], 0, 0, 0);
        acc[nt] = __builtin_amdgcn_mfma_f32_16x16x32_f16(af[1], bf[1][nt], acc[nt], 0, 0, 0);
    }

    float dv[4];
    #pragma unroll
    for (int i = 0; i < 4; i++) dv[i] = dinv[(row0 + q * 4 + i) >> 1];

    _Float16* obw = ob[wave];
    #pragma unroll
    for (int nt = 0; nt < 4; nt++)
        #pragma unroll
        for (int i = 0; i < 4; i++)
            obw[(q * 4 + i) * 72 + nt * 16 + m] = (_Float16)(acc[nt][i] * dv[i]);
    __syncthreads();

    _Float16* yp = Y + (size_t)row0 * 64;
    #pragma unroll
    for (int s = 0; s < 2; s++) {
        int c8 = s * 64 + lane;
        int r = c8 >> 3, cg = c8 & 7;
        uint4 v = *(const uint4*)(obw + r * 72 + cg * 8);
        *(uint4*)(yp + (size_t)r * 64 + cg * 8) = v;
    }
}

// ---------------- pull-style GCN aggregation (fp16, packed dense CSR) ------
// agg[n] = dinv[n] * (hw'[n] + sum_e ew_e * hw'[src_e]) + bias
// Full batches of 16 run unmasked; single masked tail batch (guard entries
// keep the over-read in-bounds).

__global__ __launch_bounds__(256) void k_prop(const __half* __restrict__ hw,
                                              const float* __restrict__ bias,
                                              const float* __restrict__ dinv,
                                              const int* __restrict__ row_ptr,
                                              const int* __restrict__ cnt,
                                              const unsigned* __restrict__ edges,
                                              __half* __restrict__ agg) {
    int t = threadIdx.x;
    int lane = t & 63;
    int n = __builtin_amdgcn_readfirstlane(blockIdx.x * 4 + (t >> 6));
    if (n >= NNODES) return;

    int f = lane * 2;            // flat half-offset in [0,128), even
    int feat = f & 63;
    const float qs = 1.0f / 32767.0f;

    float2 bv = *(const float2*)(bias + feat);
    float dv = dinv[n];
    float2 self = __half22float2(*(const __half2*)(hw + (size_t)n * 128 + f));
    float acc0 = self.x;
    float acc1 = self.y;

    int start = row_ptr[n];
    int cn    = cnt[n];
    const unsigned* pp = edges + start;

    int full = cn & ~15;
    int p = 0;
    for (; p < full; p += 16) {
        unsigned e[16];
        #pragma unroll
        for (int i = 0; i < 16; i++) e[i] = pp[p + i];
        float2 h[16];
        #pragma unroll
        for (int i = 0; i < 16; i++) {
            int s = (int)(e[i] & 0x1FFFFu);
            h[i] = __half22float2(*(const __half2*)(hw + (size_t)s * 128 + f));
        }
        #pragma unroll
        for (int i = 0; i < 16; i++) {
            float w = (float)(e[i] >> 17) * qs;
            acc0 += w * h[i].x;
            acc1 += w * h[i].y;
        }
    }
    if (p < cn) {
        unsigned e[16];
        #pragma unroll
        for (int i = 0; i < 16; i++) e[i] = pp[p + i];
        float2 h[16];
        #pragma unroll
        for (int i = 0; i < 16; i++) {
            int s = (int)(e[i] & 0x1FFFFu);
            h[i] = __half22float2(*(const __half2*)(hw + (size_t)s * 128 + f));
        }
        #pragma unroll
        for (int i = 0; i < 16; i++) {
            float w = ((p + i) < cn) ? (float)(e[i] >> 17) * qs : 0.0f;
            acc0 += w * h[i].x;
            acc1 += w * h[i].y;
        }
    }

    *(__half2*)(agg + (size_t)n * 128 + f) =
        __floats2half2_rn(dv * acc0 + bv.x, dv * acc1 + bv.y);
}

// ---------------- GraphNorm stats (sum, sumsq per column) ----------------

__global__ __launch_bounds__(256) void k_stats(const __half* __restrict__ agg,
                                               float* __restrict__ stats) {
    __shared__ float ls[16][128];
    __shared__ float lq[16][128];
    int t = threadIdx.x;
    int cb = (t & 15) * 8;
    int rg = t >> 4;
    float s[8], q[8];
    #pragma unroll
    for (int i = 0; i < 8; i++) { s[i] = 0.f; q[i] = 0.f; }
    for (int r = blockIdx.x * 16 + rg; r < NNODES; r += gridDim.x * 16) {
        uint4 u = *(const uint4*)(agg + (size_t)r * 128 + cb);
        const __half2* h2 = (const __half2*)&u;
        #pragma unroll
        for (int i = 0; i < 4; i++) {
            float2 v = __half22float2(h2[i]);
            s[2*i]   += v.x; q[2*i]   += v.x * v.x;
            s[2*i+1] += v.y; q[2*i+1] += v.y * v.y;
        }
    }
    #pragma unroll
    for (int i = 0; i < 8; i++) { ls[rg][cb + i] = s[i]; lq[rg][cb + i] = q[i]; }
    __syncthreads();
    if (t < 128) {
        float a = 0.f, b = 0.f;
        #pragma unroll
        for (int g = 0; g < 16; g++) { a += ls[g][t]; b += lq[g][t]; }
        atomicAdd(&stats[t], a);
        atomicAdd(&stats[128 + t], b);
    }
}

// ---------------- fused subgraph pooling + MLP head ----------------

__global__ __launch_bounds__(256) void k_head(const __half* __restrict__ agg,
                                              const int* __restrict__ subg,
                                              const float* __restrict__ mW1,
                                              const float* __restrict__ mb1,
                                              const float* __restrict__ mW2,
                                              const float* __restrict__ mb2,
                                              float* __restrict__ out) {
    __shared__ int   idx[64];
    __shared__ float pl[4][64];
    __shared__ float red[128];
    int s = blockIdx.x, t = threadIdx.x;
    if (t < 64) idx[t] = subg[s * 64 + t];
    __syncthreads();
    int j = t & 63, grp = t >> 6;
    float acc = 0.f;
    #pragma unroll
    for (int m = grp * 16; m < grp * 16 + 16; m++) {
        int n = idx[m];
        acc += __half2float(agg[(size_t)n * 128 + j]) +
               __half2float(agg[(size_t)n * 128 + 64 + j]);
    }
    pl[grp][j] = acc * 0.5f;
    __syncthreads();
    if (t < 64) pl[0][t] = pl[0][t] + pl[1][t] + pl[2][t] + pl[3][t];
    __syncthreads();
    if (t < 128) {
        float h = mb1[t];
        #pragma unroll
        for (int k = 0; k < 64; k++) h += pl[0][k] * mW1[k * 128 + t];
        h = fmaxf(h, 0.0f);
        red[t] = h * mW2[t];
    }
    __syncthreads();
    for (int off = 64; off > 0; off >>= 1) {
        if (t < off) red[t] += red[t + off];
        __syncthreads();
    }
    if (t == 0) out[s] = red[0] + mb2[0];
}

// ---------------- launcher ----------------

extern "C" void kernel_launch(void* const* d_in, const int* in_sizes, int n_in,
                              void* d_out, int out_size, void* d_ws, size_t ws_size,
                              hipStream_t stream) {
    const float* x     = (const float*)d_in[0];
    const int*   ei    = (const int*)d_in[1];
    const float* ew    = (const float*)d_in[2];
    const int*   subg  = (const int*)d_in[3];
    const float* W1    = (const float*)d_in[4];
    const float* b1    = (const float*)d_in[5];
    const float* gn_w  = (const float*)d_in[6];
    const float* gn_b  = (const float*)d_in[7];
    const float* gn_ms = (const float*)d_in[8];
    const float* W2    = (const float*)d_in[9];
    const float* b2    = (const float*)d_in[10];
    const float* mW1   = (const float*)d_in[11];
    const float* mb1   = (const float*)d_in[12];
    const float* mW2   = (const float*)d_in[13];
    const float* mb2   = (const float*)d_in[14];
    float* out = (float*)d_out;

    char* w = (char*)d_ws;
    size_t off = 0;
    auto alloc = [&](size_t bytes) {
        void* p = w + off;
        off = (off + bytes + 255) & ~(size_t)255;
        return p;
    };
    float*    dinv    = (float*)   alloc((size_t)NNODES * 4);
    int*      cnt     = (int*)     alloc((size_t)NNODES * 4);
    int*      row_ptr = (int*)     alloc((size_t)NNODES * 4);
    unsigned* edges   = (unsigned*)alloc(((size_t)NEDGES + 16) * 4);  // 6.4 MB +guard
    int2*     esw     = (int2*)    alloc((size_t)NEDGES * 8);         // 12.8 MB
    __half*   hw      = (__half*)  alloc((size_t)NNODES * 128 * 2);   // 25.6 MB
    __half*   agg     = (__half*)  alloc((size_t)NNODES * 128 * 2);   // 25.6 MB
    float*    stats   = (float*)   alloc(512 * 4);
    int*      block_counts = (int*)alloc((size_t)NBLK * NWIN * 4);
    int*      block_off    = (int*)alloc((size_t)NBLK * NWIN * 4);
    int*      win_base     = (int*)alloc(NWIN * 4);
    int*      win_lim      = (int*)alloc(NWIN * 4);
    int*      cursor       = (int*)alloc(256);

    const int* src = ei;
    const int* dst = ei + NEDGES;

    // edge binning (counting sort by 512-node dst window) -> packed CSR + dinv
    k_hist   <<<NBLK, 256, 0, stream>>>(dst, block_counts, cursor);
    k_off    <<<NWIN, 256, 0, stream>>>(block_counts, cursor, win_base, win_lim,
                                        block_off, stats, edges);
    k_scatter<<<NBLK, 256, 0, stream>>>(src, dst, ew, block_off, esw);
    k_fill2  <<<NWIN, 256, 0, stream>>>(win_base, win_lim, esw, edges, row_ptr, cnt, dinv);

    // layer 1
    k_gemm<false><<<3125, 256, 0, stream>>>(x, W1, dinv, (_Float16*)hw,
                                            nullptr, nullptr, nullptr, nullptr);
    k_prop<<<25000, 256, 0, stream>>>(hw, b1, dinv, row_ptr, cnt, edges, agg);

    // GraphNorm stats
    k_stats<<<512, 256, 0, stream>>>(agg, stats);

    // layer 2 (GraphNorm coef + affine + ReLU fused into GEMM2)
    k_gemm<true><<<3125, 256, 0, stream>>>(agg, W2, dinv, (_Float16*)hw,
                                           stats, gn_w, gn_b, gn_ms);
    k_prop<<<25000, 256, 0, stream>>>(hw, b2, dinv, row_ptr, cnt, edges, agg);

    // fused pooling + MLP head
    k_head<<<NSUB, 256, 0, stream>>>(agg, subg, mW1, mb1, mW2, mb2, out);
}

// Round 10
// 338.545 us; speedup vs baseline: 1.8238x; 1.0474x over previous
//
#include <hip/hip_runtime.h>
#include <hip/hip_fp16.h>

#define NNODES 100000
#define NEDGES 1600000
#define NSUB   1000
#define MSUB   64
#define MHID   128

#define WSHIFT 9                         // 512-node dst windows
#define WIN    512
#define NWIN   ((NNODES + 511) >> 9)     // 196
#define NBLK   256                       // blocks for hist/scatter
#define CHUNK  (NEDGES / NBLK)           // 6250 exact

typedef _Float16 f16x8 __attribute__((ext_vector_type(8)));
typedef float    f32x4 __attribute__((ext_vector_type(4)));

// ---------------- edge binning: counting sort by dst window ----------------
// Also marks head-needed nodes (flags[subg[i]] = 1) — layer-2 aggregation is
// only consumed through subG pooling, so prop2 can skip unmarked nodes.
// No memset needed: the test is an exact ==1 compare, and a spurious match on
// poisoned memory only causes harmless extra work (never wrong values).

__global__ __launch_bounds__(256) void k_hist(const int* __restrict__ dst,
                                              int* __restrict__ block_counts,
                                              int* __restrict__ cursor,
                                              const int* __restrict__ subg,
                                              int* __restrict__ flags) {
    __shared__ int hist[NWIN];
    int t = threadIdx.x, b = blockIdx.x;
    if (b == 0 && t == 0) *cursor = 0;
    if (t < 250) flags[subg[b * 250 + t]] = 1;    // 256*250 = 64000 exact
    for (int i = t; i < NWIN; i += 256) hist[i] = 0;
    __syncthreads();
    int e0 = b * CHUNK;
    for (int e = e0 + t; e < e0 + CHUNK; e += 256)
        atomicAdd(&hist[dst[e] >> WSHIFT], 1);
    __syncthreads();
    for (int i = t; i < NWIN; i += 256) block_counts[b * NWIN + i] = hist[i];
}

// one block per window: total (reduce) -> base (atomic cursor; window order in
// the CSR is arbitrary but contiguous) -> per-block offsets (scan). Also zeroes
// stats and writes the prop guard entries (block 0).
__global__ __launch_bounds__(256) void k_off(const int* __restrict__ block_counts,
                                             int* __restrict__ cursor,
                                             int* __restrict__ win_base,
                                             int* __restrict__ win_lim,
                                             int* __restrict__ block_off,
                                             float* __restrict__ stats,
                                             unsigned* __restrict__ edges) {
    __shared__ int arr[256];
    __shared__ int red[256];
    __shared__ int base_s;
    int t = threadIdx.x, w = blockIdx.x;
    int own = block_counts[t * NWIN + w];
    arr[t] = own; red[t] = own;
    __syncthreads();
    for (int off = 128; off > 0; off >>= 1) {
        if (t < off) red[t] += red[t + off];
        __syncthreads();
    }
    if (t == 0) base_s = atomicAdd(cursor, red[0]);
    for (int off = 1; off < 256; off <<= 1) {
        int v = (t >= off) ? arr[t - off] : 0;
        __syncthreads();
        arr[t] += v;
        __syncthreads();
    }
    int base = base_s;
    block_off[t * NWIN + w] = base + arr[t] - own;
    if (t == 0) { win_base[w] = base; win_lim[w] = base + red[0]; }
    if (w == 0) {
        stats[t] = 0.0f; stats[t + 256] = 0.0f;
        if (t < 16) edges[NEDGES + t] = 0u;
    }
}

__global__ __launch_bounds__(256) void k_scatter(const int* __restrict__ src,
                                                 const int* __restrict__ dst,
                                                 const float* __restrict__ ew,
                                                 const int* __restrict__ block_off,
                                                 int2* __restrict__ esw) {
    __shared__ int myoff[NWIN];
    int t = threadIdx.x, b = blockIdx.x;
    for (int i = t; i < NWIN; i += 256) myoff[i] = block_off[b * NWIN + i];
    __syncthreads();
    int e0 = b * CHUNK;
    for (int e = e0 + t; e < e0 + CHUNK; e += 256) {
        int d = dst[e];
        int w = d >> WSHIFT;
        int pos = atomicAdd(&myoff[w], 1);
        int dl = d - (w << WSHIFT);
        esw[pos] = make_int2((dl << 17) | src[e], __float_as_int(ew[e]));
    }
}

// one block per window: dense CSR (4 B packed entries: wq15<<17 | src17) +
// raw-weight degree sums -> dinv.
__global__ __launch_bounds__(256) void k_fill2(const int* __restrict__ win_base,
                                               const int* __restrict__ win_lim,
                                               const int2* __restrict__ esw,
                                               unsigned* __restrict__ edges,
                                               int* __restrict__ row_ptr,
                                               int* __restrict__ cnt,
                                               float* __restrict__ dinv) {
    __shared__ int   cnt_l[WIN];
    __shared__ int   sc[WIN];
    __shared__ int   fill_l[WIN];
    __shared__ float degw[WIN];
    int t = threadIdx.x, w = blockIdx.x;
    #pragma unroll
    for (int i = t; i < WIN; i += 256) { cnt_l[i] = 0; fill_l[i] = 0; degw[i] = 0.f; }
    __syncthreads();
    int e0 = win_base[w], e1 = win_lim[w];
    for (int e = e0 + t; e < e1; e += 256) {
        int2 v = esw[e];
        int dl = ((unsigned)v.x) >> 17;
        atomicAdd(&cnt_l[dl], 1);
        atomicAdd(&degw[dl], __int_as_float(v.y));
    }
    __syncthreads();
    sc[t] = cnt_l[t]; sc[t + 256] = cnt_l[t + 256];
    __syncthreads();
    for (int off = 1; off < WIN; off <<= 1) {
        int v0 = (t >= off) ? sc[t - off] : 0;
        int v1 = (t + 256 >= off) ? sc[t + 256 - off] : 0;
        __syncthreads();
        sc[t] += v0; sc[t + 256] += v1;
        __syncthreads();
    }
    sc[t]       = e0 + sc[t]       - cnt_l[t];
    sc[t + 256] = e0 + sc[t + 256] - cnt_l[t + 256];
    __syncthreads();
    for (int e = e0 + t; e < e1; e += 256) {
        int2 v = esw[e];
        int dl = ((unsigned)v.x) >> 17;
        int pos = sc[dl] + atomicAdd(&fill_l[dl], 1);
        int wq = __float2int_rn(__int_as_float(v.y) * 32767.0f);
        edges[pos] = ((unsigned)wq << 17) | ((unsigned)v.x & 0x1FFFFu);
    }
    __syncthreads();
    #pragma unroll
    for (int i = t; i < WIN; i += 256) {
        int node = (w << WSHIFT) + i;
        if (node < NNODES) {
            row_ptr[node] = sc[i];
            cnt[node]     = cnt_l[i];
            dinv[node]    = rsqrtf(degw[i] + 1.0f);
        }
    }
}

// ---------------- MFMA GEMM: [200000 x 64] @ [64 x 64] -> fp16, row-scaled --
// Wave = one 16x64 tile, K=64: 8 x mfma_f32_16x16x32_f16. TR=true computes
// GraphNorm coefs per-thread from stats (k_coef folded in).

template <bool TR>
__global__ __launch_bounds__(256) void k_gemm(const void* __restrict__ Xv,
                                              const float* __restrict__ Wg,
                                              const float* __restrict__ dinv,
                                              _Float16* __restrict__ Y,
                                              const float* __restrict__ stats,
                                              const float* __restrict__ gn_w,
                                              const float* __restrict__ gn_b,
                                              const float* __restrict__ gn_ms) {
    __shared__ __align__(16) _Float16 ob[4][16 * 72];   // per-wave 16x64 (+pad 8)
    int t = threadIdx.x;
    int wave = t >> 6, lane = t & 63;
    int m = lane & 15, q = lane >> 4;

    // B fragments: B[k = kb*32 + q*8 + j][n = nt*16 + m]
    f16x8 bf[2][4];
    #pragma unroll
    for (int kb = 0; kb < 2; kb++)
        #pragma unroll
        for (int nt = 0; nt < 4; nt++)
            #pragma unroll
            for (int j = 0; j < 8; j++)
                bf[kb][nt][j] = (_Float16)Wg[(kb * 32 + q * 8 + j) * 64 + nt * 16 + m];

    float ca[16], cb[16];
    if constexpr (TR) {
        int c = m & 1;     // row = n*2+c -> channel = m & 1
        const float inv_n = 1.0f / (float)NNODES;
        #pragma unroll
        for (int kb = 0; kb < 2; kb++)
            #pragma unroll
            for (int j = 0; j < 8; j++) {
                int k = kb * 32 + q * 8 + j;
                int col = c * 64 + k;
                float mean = stats[col] * inv_n;
                float eh2  = stats[128 + col] * inv_n;
                float ms   = gn_ms[k];
                float mm   = ms * mean;
                float var  = eh2 - 2.0f * mm * mean + mm * mm;
                float A = gn_w[k] * rsqrtf(var + 1e-5f);
                ca[kb * 8 + j] = A;
                cb[kb * 8 + j] = gn_b[k] - A * mm;
            }
    }

    int tile = blockIdx.x * 4 + wave;
    int row0 = tile * 16;

    f16x8 af[2];
    if constexpr (!TR) {
        const float* xp = (const float*)Xv + (size_t)(row0 + m) * 64;
        #pragma unroll
        for (int kb = 0; kb < 2; kb++) {
            float4 u0 = *(const float4*)(xp + kb * 32 + q * 8);
            float4 u1 = *(const float4*)(xp + kb * 32 + q * 8 + 4);
            af[kb][0] = (_Float16)u0.x; af[kb][1] = (_Float16)u0.y;
            af[kb][2] = (_Float16)u0.z; af[kb][3] = (_Float16)u0.w;
            af[kb][4] = (_Float16)u1.x; af[kb][5] = (_Float16)u1.y;
            af[kb][6] = (_Float16)u1.z; af[kb][7] = (_Float16)u1.w;
        }
    } else {
        const _Float16* xp = (const _Float16*)Xv + (size_t)(row0 + m) * 64;
        #pragma unroll
        for (int kb = 0; kb < 2; kb++) {
            f16x8 v = *(const f16x8*)(xp + kb * 32 + q * 8);
            #pragma unroll
            for (int j = 0; j < 8; j++) {
                float f = (float)v[j];
                f = fmaxf(ca[kb * 8 + j] * f + cb[kb * 8 + j], 0.0f);
                af[kb][j] = (_Float16)f;
            }
        }
    }

    f32x4 acc[4];
    #pragma unroll
    for (int nt = 0; nt < 4; nt++) {
        acc[nt] = (f32x4){0.f, 0.f, 0.f, 0.f};
        acc[nt] = __builtin_amdgcn_mfma_f32_16x16x32_f16(af[0], bf[0][nt], acc[nt], 0, 0, 0);
        acc[nt] = __builtin_amdgcn_mfma_f32_16x16x32_f16(af[1], bf[1][nt], acc[nt], 0, 0, 0);
    }

    float dv[4];
    #pragma unroll
    for (int i = 0; i < 4; i++) dv[i] = dinv[(row0 + q * 4 + i) >> 1];

    _Float16* obw = ob[wave];
    #pragma unroll
    for (int nt = 0; nt < 4; nt++)
        #pragma unroll
        for (int i = 0; i < 4; i++)
            obw[(q * 4 + i) * 72 + nt * 16 + m] = (_Float16)(acc[nt][i] * dv[i]);
    __syncthreads();

    _Float16* yp = Y + (size_t)row0 * 64;
    #pragma unroll
    for (int s = 0; s < 2; s++) {
        int c8 = s * 64 + lane;
        int r = c8 >> 3, cg = c8 & 7;
        uint4 v = *(const uint4*)(obw + r * 72 + cg * 8);
        *(uint4*)(yp + (size_t)r * 64 + cg * 8) = v;
    }
}

// ---------------- pull-style GCN aggregation (fp16, packed dense CSR) ------
// agg[n] = dinv[n] * (hw'[n] + sum_e ew_e * hw'[src_e]) + bias
// USE_FLAGS (layer 2): skip nodes not referenced by any subgraph — their agg
// is never read downstream. Wave-uniform early-out.

template <bool USE_FLAGS>
__global__ __launch_bounds__(256) void k_prop(const __half* __restrict__ hw,
                                              const float* __restrict__ bias,
                                              const float* __restrict__ dinv,
                                              const int* __restrict__ row_ptr,
                                              const int* __restrict__ cnt,
                                              const unsigned* __restrict__ edges,
                                              const int* __restrict__ flags,
                                              __half* __restrict__ agg) {
    int t = threadIdx.x;
    int lane = t & 63;
    int n = __builtin_amdgcn_readfirstlane(blockIdx.x * 4 + (t >> 6));
    if (n >= NNODES) return;
    if constexpr (USE_FLAGS) { if (flags[n] != 1) return; }

    int f = lane * 2;            // flat half-offset in [0,128), even
    int feat = f & 63;
    const float qs = 1.0f / 32767.0f;

    float2 bv = *(const float2*)(bias + feat);
    float dv = dinv[n];
    float2 self = __half22float2(*(const __half2*)(hw + (size_t)n * 128 + f));
    float acc0 = self.x;
    float acc1 = self.y;

    int start = row_ptr[n];
    int cn    = cnt[n];
    const unsigned* pp = edges + start;

    int full = cn & ~15;
    int p = 0;
    for (; p < full; p += 16) {
        unsigned e[16];
        #pragma unroll
        for (int i = 0; i < 16; i++) e[i] = pp[p + i];
        float2 h[16];
        #pragma unroll
        for (int i = 0; i < 16; i++) {
            int s = (int)(e[i] & 0x1FFFFu);
            h[i] = __half22float2(*(const __half2*)(hw + (size_t)s * 128 + f));
        }
        #pragma unroll
        for (int i = 0; i < 16; i++) {
            float w = (float)(e[i] >> 17) * qs;
            acc0 += w * h[i].x;
            acc1 += w * h[i].y;
        }
    }
    if (p < cn) {
        unsigned e[16];
        #pragma unroll
        for (int i = 0; i < 16; i++) e[i] = pp[p + i];
        float2 h[16];
        #pragma unroll
        for (int i = 0; i < 16; i++) {
            int s = (int)(e[i] & 0x1FFFFu);
            h[i] = __half22float2(*(const __half2*)(hw + (size_t)s * 128 + f));
        }
        #pragma unroll
        for (int i = 0; i < 16; i++) {
            float w = ((p + i) < cn) ? (float)(e[i] >> 17) * qs : 0.0f;
            acc0 += w * h[i].x;
            acc1 += w * h[i].y;
        }
    }

    *(__half2*)(agg + (size_t)n * 128 + f) =
        __floats2half2_rn(dv * acc0 + bv.x, dv * acc1 + bv.y);
}

// ---------------- GraphNorm stats (sum, sumsq per column) ----------------

__global__ __launch_bounds__(256) void k_stats(const __half* __restrict__ agg,
                                               float* __restrict__ stats) {
    __shared__ float ls[16][128];
    __shared__ float lq[16][128];
    int t = threadIdx.x;
    int cb = (t & 15) * 8;
    int rg = t >> 4;
    float s[8], q[8];
    #pragma unroll
    for (int i = 0; i < 8; i++) { s[i] = 0.f; q[i] = 0.f; }
    for (int r = blockIdx.x * 16 + rg; r < NNODES; r += gridDim.x * 16) {
        uint4 u = *(const uint4*)(agg + (size_t)r * 128 + cb);
        const __half2* h2 = (const __half2*)&u;
        #pragma unroll
        for (int i = 0; i < 4; i++) {
            float2 v = __half22float2(h2[i]);
            s[2*i]   += v.x; q[2*i]   += v.x * v.x;
            s[2*i+1] += v.y; q[2*i+1] += v.y * v.y;
        }
    }
    #pragma unroll
    for (int i = 0; i < 8; i++) { ls[rg][cb + i] = s[i]; lq[rg][cb + i] = q[i]; }
    __syncthreads();
    if (t < 128) {
        float a = 0.f, b = 0.f;
        #pragma unroll
        for (int g = 0; g < 16; g++) { a += ls[g][t]; b += lq[g][t]; }
        atomicAdd(&stats[t], a);
        atomicAdd(&stats[128 + t], b);
    }
}

// ---------------- fused subgraph pooling + MLP head ----------------

__global__ __launch_bounds__(256) void k_head(const __half* __restrict__ agg,
                                              const int* __restrict__ subg,
                                              const float* __restrict__ mW1,
                                              const float* __restrict__ mb1,
                                              const float* __restrict__ mW2,
                                              const float* __restrict__ mb2,
                                              float* __restrict__ out) {
    __shared__ int   idx[64];
    __shared__ float pl[4][64];
    __shared__ float red[128];
    int s = blockIdx.x, t = threadIdx.x;
    if (t < 64) idx[t] = subg[s * 64 + t];
    __syncthreads();
    int j = t & 63, grp = t >> 6;
    float acc = 0.f;
    #pragma unroll
    for (int m = grp * 16; m < grp * 16 + 16; m++) {
        int n = idx[m];
        acc += __half2float(agg[(size_t)n * 128 + j]) +
               __half2float(agg[(size_t)n * 128 + 64 + j]);
    }
    pl[grp][j] = acc * 0.5f;
    __syncthreads();
    if (t < 64) pl[0][t] = pl[0][t] + pl[1][t] + pl[2][t] + pl[3][t];
    __syncthreads();
    if (t < 128) {
        float h = mb1[t];
        #pragma unroll
        for (int k = 0; k < 64; k++) h += pl[0][k] * mW1[k * 128 + t];
        h = fmaxf(h, 0.0f);
        red[t] = h * mW2[t];
    }
    __syncthreads();
    for (int off = 64; off > 0; off >>= 1) {
        if (t < off) red[t] += red[t + off];
        __syncthreads();
    }
    if (t == 0) out[s] = red[0] + mb2[0];
}

// ---------------- launcher ----------------

extern "C" void kernel_launch(void* const* d_in, const int* in_sizes, int n_in,
                              void* d_out, int out_size, void* d_ws, size_t ws_size,
                              hipStream_t stream) {
    const float* x     = (const float*)d_in[0];
    const int*   ei    = (const int*)d_in[1];
    const float* ew    = (const float*)d_in[2];
    const int*   subg  = (const int*)d_in[3];
    const float* W1    = (const float*)d_in[4];
    const float* b1    = (const float*)d_in[5];
    const float* gn_w  = (const float*)d_in[6];
    const float* gn_b  = (const float*)d_in[7];
    const float* gn_ms = (const float*)d_in[8];
    const float* W2    = (const float*)d_in[9];
    const float* b2    = (const float*)d_in[10];
    const float* mW1   = (const float*)d_in[11];
    const float* mb1   = (const float*)d_in[12];
    const float* mW2   = (const float*)d_in[13];
    const float* mb2   = (const float*)d_in[14];
    float* out = (float*)d_out;

    char* w = (char*)d_ws;
    size_t off = 0;
    auto alloc = [&](size_t bytes) {
        void* p = w + off;
        off = (off + bytes + 255) & ~(size_t)255;
        return p;
    };
    float*    dinv    = (float*)   alloc((size_t)NNODES * 4);
    int*      cnt     = (int*)     alloc((size_t)NNODES * 4);
    int*      row_ptr = (int*)     alloc((size_t)NNODES * 4);
    int*      flags   = (int*)     alloc((size_t)NNODES * 4);
    unsigned* edges   = (unsigned*)alloc(((size_t)NEDGES + 16) * 4);  // 6.4 MB +guard
    int2*     esw     = (int2*)    alloc((size_t)NEDGES * 8);         // 12.8 MB
    __half*   hw      = (__half*)  alloc((size_t)NNODES * 128 * 2);   // 25.6 MB
    __half*   agg     = (__half*)  alloc((size_t)NNODES * 128 * 2);   // 25.6 MB
    float*    stats   = (float*)   alloc(512 * 4);
    int*      block_counts = (int*)alloc((size_t)NBLK * NWIN * 4);
    int*      block_off    = (int*)alloc((size_t)NBLK * NWIN * 4);
    int*      win_base     = (int*)alloc(NWIN * 4);
    int*      win_lim      = (int*)alloc(NWIN * 4);
    int*      cursor       = (int*)alloc(256);

    const int* src = ei;
    const int* dst = ei + NEDGES;

    // edge binning (counting sort by 512-node dst window) -> packed CSR + dinv
    k_hist   <<<NBLK, 256, 0, stream>>>(dst, block_counts, cursor, subg, flags);
    k_off    <<<NWIN, 256, 0, stream>>>(block_counts, cursor, win_base, win_lim,
                                        block_off, stats, edges);
    k_scatter<<<NBLK, 256, 0, stream>>>(src, dst, ew, block_off, esw);
    k_fill2  <<<NWIN, 256, 0, stream>>>(win_base, win_lim, esw, edges, row_ptr, cnt, dinv);

    // layer 1
    k_gemm<false><<<3125, 256, 0, stream>>>(x, W1, dinv, (_Float16*)hw,
                                            nullptr, nullptr, nullptr, nullptr);
    k_prop<false><<<25000, 256, 0, stream>>>(hw, b1, dinv, row_ptr, cnt, edges,
                                             nullptr, agg);

    // GraphNorm stats
    k_stats<<<512, 256, 0, stream>>>(agg, stats);

    // layer 2 (GraphNorm coef + affine + ReLU fused into GEMM2)
    k_gemm<true><<<3125, 256, 0, stream>>>(agg, W2, dinv, (_Float16*)hw,
                                           stats, gn_w, gn_b, gn_ms);
    k_prop<true><<<25000, 256, 0, stream>>>(hw, b2, dinv, row_ptr, cnt, edges,
                                            flags, agg);

    // fused pooling + MLP head
    k_head<<<NSUB, 256, 0, stream>>>(agg, subg, mW1, mb1, mW2, mb2, out);
}